// Round 6
// baseline (1010.412 us; speedup 1.0000x reference)
//
#include <hip/hip_runtime.h>
#include <hip/hip_cooperative_groups.h>
#include <hip/hip_bf16.h>

#define IN_DIM 1024
#define HID 128
#define LAT 64
#define DEGPAD 128

typedef __attribute__((ext_vector_type(8))) short bf16x8;
typedef __attribute__((ext_vector_type(4))) short bf16x4;
typedef __attribute__((ext_vector_type(4))) float f32x4;

// weight-transpose-split arena offsets (bf16 elements)
#define W1T_OFF 0
#define W2T_OFF 131072
#define Wa1T_OFF 139264
#define Wa2T_OFF 147456
#define WsT_OFF 278528
#define WT_TOTAL 282624

struct MegaArgs {
    const float* x; const int* ei;
    const float* W1; const float* b1; const float* W2; const float* b2;
    const float* Wa1; const float* ba1; const float* Wa2; const float* ba2;
    const float* Ws; const float* bs;
    float* attr; float* st; float* zout;
    int* colPad; int* cursor;
    __hip_bfloat16* Whi; __hip_bfloat16* Wlo;
    float* t128; float* t64;
    __hip_bfloat16* Hhi; __hip_bfloat16* Hlo;
    __hip_bfloat16* AZhi; __hip_bfloat16* AZlo;
    __hip_bfloat16* AAhi; __hip_bfloat16* AAlo;
    __hip_bfloat16* Shi; __hip_bfloat16* Slo;
    int N; int E; int Mpad;
    int coop; int ph_lo; int ph_hi;
};

__device__ __forceinline__ void splitf(float v, __hip_bfloat16& h, __hip_bfloat16& l) {
    h = __float2bfloat16(v);
    l = __float2bfloat16(v - __bfloat162float(h));
}

// ---------- dense GEMM tile (block tile 128x64, 4 waves 2x2, wave tile 64x32) ----------
// AMODE 0: A as hi/lo bf16 (rows < Mpad valid memory); AMODE 1: A fp32 row-guarded, in-reg split.

template<int AMODE, bool BIAS, bool RELU, bool SPLITOUT, bool NT>
__device__ void dev_gemm(float* smem, int bx, int byy,
        const __hip_bfloat16* __restrict__ Ahi, const __hip_bfloat16* __restrict__ Alo,
        const float* __restrict__ Af,
        const __hip_bfloat16* __restrict__ Bthi, const __hip_bfloat16* __restrict__ Btlo,
        const float* __restrict__ bias,
        float* __restrict__ Cf, __hip_bfloat16* __restrict__ Chi, __hip_bfloat16* __restrict__ Clo,
        int M, int K, int Nc) {
    int tid = threadIdx.x;
    int w = tid >> 6, lane = tid & 63;
    int wr = w >> 1, wc = w & 1;
    int m0 = byy * 128, n0 = bx * 64;
    int lrow = lane & 15, lk = (lane >> 4) * 8;

    int arow[4];
    size_t aoff[4];
#pragma unroll
    for (int mi = 0; mi < 4; ++mi) {
        arow[mi] = m0 + wr * 64 + mi * 16 + lrow;
        aoff[mi] = (size_t)arow[mi] * K + lk;
    }
    size_t boff[2];
#pragma unroll
    for (int nj = 0; nj < 2; ++nj)
        boff[nj] = (size_t)(n0 + wc * 32 + nj * 16 + lrow) * K + lk;

    f32x4 acc[4][2] = {};

    for (int k0 = 0; k0 < K; k0 += 32) {
        bf16x8 bh[2], bl[2], ah[4], al[4];
#pragma unroll
        for (int nj = 0; nj < 2; ++nj) {
            bh[nj] = *(const bf16x8*)(Bthi + boff[nj] + k0);
            bl[nj] = *(const bf16x8*)(Btlo + boff[nj] + k0);
        }
        if constexpr (AMODE == 0) {
#pragma unroll
            for (int mi = 0; mi < 4; ++mi) {
                ah[mi] = *(const bf16x8*)(Ahi + aoff[mi] + k0);
                al[mi] = *(const bf16x8*)(Alo + aoff[mi] + k0);
            }
        } else {
#pragma unroll
            for (int mi = 0; mi < 4; ++mi) {
                float4 f0 = make_float4(0.f, 0.f, 0.f, 0.f), f1 = f0;
                if (arow[mi] < M) {
                    f0 = *(const float4*)(Af + aoff[mi] + k0);
                    f1 = *(const float4*)(Af + aoff[mi] + k0 + 4);
                }
                float ff[8] = {f0.x, f0.y, f0.z, f0.w, f1.x, f1.y, f1.z, f1.w};
                __attribute__((aligned(16))) __hip_bfloat16 hb[8], lb[8];
#pragma unroll
                for (int t = 0; t < 8; ++t) splitf(ff[t], hb[t], lb[t]);
                ah[mi] = *(const bf16x8*)hb;
                al[mi] = *(const bf16x8*)lb;
            }
        }
#pragma unroll
        for (int mi = 0; mi < 4; ++mi)
#pragma unroll
            for (int nj = 0; nj < 2; ++nj) {
                acc[mi][nj] = __builtin_amdgcn_mfma_f32_16x16x32_bf16(ah[mi], bh[nj], acc[mi][nj], 0, 0, 0);
                acc[mi][nj] = __builtin_amdgcn_mfma_f32_16x16x32_bf16(ah[mi], bl[nj], acc[mi][nj], 0, 0, 0);
                acc[mi][nj] = __builtin_amdgcn_mfma_f32_16x16x32_bf16(al[mi], bh[nj], acc[mi][nj], 0, 0, 0);
            }
    }

    // stage to LDS (C/D frag: col=lane&15, row=(lane>>4)*4+r)
    int r0 = (lane >> 4) * 4;
#pragma unroll
    for (int mi = 0; mi < 4; ++mi)
#pragma unroll
        for (int nj = 0; nj < 2; ++nj) {
            int cl = wc * 32 + nj * 16 + lrow;
#pragma unroll
            for (int r = 0; r < 4; ++r) {
                int rl = wr * 64 + mi * 16 + r0 + r;
                smem[rl * 68 + cl] = acc[mi][nj][r];
            }
        }
    __syncthreads();

#pragma unroll
    for (int it = 0; it < 8; ++it) {
        int rl = it * 16 + (tid >> 4);
        int c4 = tid & 15;
        int row = m0 + rl;
        if (row < M) {
            int col = n0 + c4 * 4;
            float4 v = *(const float4*)&smem[rl * 68 + c4 * 4];
            if (BIAS) {
                float4 b = *(const float4*)&bias[col];
                v.x += b.x; v.y += b.y; v.z += b.z; v.w += b.w;
            }
            if (RELU) {
                v.x = fmaxf(v.x, 0.f); v.y = fmaxf(v.y, 0.f);
                v.z = fmaxf(v.z, 0.f); v.w = fmaxf(v.w, 0.f);
            }
            if constexpr (SPLITOUT) {
                float vv[4] = {v.x, v.y, v.z, v.w};
                __attribute__((aligned(8))) __hip_bfloat16 hs[4], ls[4];
#pragma unroll
                for (int k = 0; k < 4; ++k) splitf(vv[k], hs[k], ls[k]);
                *(bf16x4*)&Chi[(size_t)row * Nc + col] = *(bf16x4*)hs;
                *(bf16x4*)&Clo[(size_t)row * Nc + col] = *(bf16x4*)ls;
            } else if constexpr (NT) {
                __builtin_nontemporal_store(*(const f32x4*)&v, (f32x4*)&Cf[(size_t)row * Nc + col]);
            } else {
                *(float4*)&Cf[(size_t)row * Nc + col] = v;
            }
        }
    }
    __syncthreads();
}

// ---------- SpMM row (one wave per row), dis on the fly from cursor ----------

template<int F, bool BIAS, bool RELU, int OMODE>   // OMODE 0: fp32; 1: split bf16
__device__ void dev_spmm(const float* __restrict__ Hin,
                         const int* __restrict__ colPad, const int* __restrict__ cursor,
                         const float* __restrict__ bias,
                         float* __restrict__ out,
                         __hip_bfloat16* __restrict__ ohi, __hip_bfloat16* __restrict__ olo,
                         int n) {
    int gw = (blockIdx.x * 256 + threadIdx.x) >> 6;
    int nw = (gridDim.x * 256) >> 6;
    int lane = threadIdx.x & 63;
    for (int i = gw; i < n; i += nw) {
        int d = cursor[i];
        float di = rsqrtf((float)(d + 1));
        if (d > DEGPAD) d = DEGPAD;
        const int* cp = colPad + (size_t)i * DEGPAD;
        float acc[F / 64];
        const float* self = Hin + (size_t)i * F;
#pragma unroll
        for (int j = 0; j < F / 64; ++j) acc[j] = di * self[lane + 64 * j];
        for (int p = 0; p < d; ++p) {
            int c = cp[p];
            float dc = rsqrtf((float)(cursor[c] + 1));
            const float* row = Hin + (size_t)c * F;
#pragma unroll
            for (int j = 0; j < F / 64; ++j) acc[j] = fmaf(dc, row[lane + 64 * j], acc[j]);
        }
#pragma unroll
        for (int j = 0; j < F / 64; ++j) {
            float r = acc[j] * di;
            if (BIAS) r += bias[lane + 64 * j];
            if (RELU) r = fmaxf(r, 0.f);
            size_t idx = (size_t)i * F + lane + 64 * j;
            if constexpr (OMODE == 1) {
                __hip_bfloat16 h, l;
                splitf(r, h, l);
                ohi[idx] = h; olo[idx] = l;
            } else {
                out[idx] = r;
            }
        }
    }
}

// ---------- sst half tile: rows I..I+127, cols J..J+63; mirror off-diagonal ----------

__device__ void dev_sst(float* smem, int bi, int bj64,
                        const __hip_bfloat16* __restrict__ Shi, const __hip_bfloat16* __restrict__ Slo,
                        float* __restrict__ C, int M) {
    int tid = threadIdx.x;
    int w = tid >> 6, lane = tid & 63;
    int wr = w >> 1, wc = w & 1;
    int I = bi * 128, J = bj64 * 64;
    int i0 = I + wr * 64, j0 = J + wc * 32;
    int lrow = lane & 15, lk = (lane >> 4) * 8;

    f32x4 acc[4][2] = {};
#pragma unroll
    for (int ks = 0; ks < 2; ++ks) {
        bf16x8 ah[4], al[4], bh[2], bl[2];
#pragma unroll
        for (int mi = 0; mi < 4; ++mi) {
            size_t off = (size_t)(i0 + mi * 16 + lrow) * 64 + ks * 32 + lk;
            ah[mi] = *(const bf16x8*)(Shi + off);
            al[mi] = *(const bf16x8*)(Slo + off);
        }
#pragma unroll
        for (int nj = 0; nj < 2; ++nj) {
            size_t off = (size_t)(j0 + nj * 16 + lrow) * 64 + ks * 32 + lk;
            bh[nj] = *(const bf16x8*)(Shi + off);
            bl[nj] = *(const bf16x8*)(Slo + off);
        }
#pragma unroll
        for (int mi = 0; mi < 4; ++mi)
#pragma unroll
            for (int nj = 0; nj < 2; ++nj) {
                acc[mi][nj] = __builtin_amdgcn_mfma_f32_16x16x32_bf16(ah[mi], bh[nj], acc[mi][nj], 0, 0, 0);
                acc[mi][nj] = __builtin_amdgcn_mfma_f32_16x16x32_bf16(ah[mi], bl[nj], acc[mi][nj], 0, 0, 0);
                acc[mi][nj] = __builtin_amdgcn_mfma_f32_16x16x32_bf16(al[mi], bh[nj], acc[mi][nj], 0, 0, 0);
            }
    }

    // stage with XOR swizzle (c4s = c4 ^ (row&15)) for conflict-tolerant transposed reads
    int r0 = (lane >> 4) * 4;
#pragma unroll
    for (int mi = 0; mi < 4; ++mi)
#pragma unroll
        for (int nj = 0; nj < 2; ++nj) {
            int cl = wc * 32 + nj * 16 + lrow;
#pragma unroll
            for (int r = 0; r < 4; ++r) {
                int rl = wr * 64 + mi * 16 + r0 + r;
                int c4s = (cl >> 2) ^ (rl & 15);
                smem[rl * 68 + (c4s << 2) + (cl & 3)] = acc[mi][nj][r];
            }
        }
    __syncthreads();

    // normal write: 128 rows x 64 cols (M % 4 == 0 -> full float4 when col < M)
#pragma unroll
    for (int it = 0; it < 8; ++it) {
        int rl = it * 16 + (tid >> 4);
        int c4 = tid & 15;
        int row = I + rl, col = J + c4 * 4;
        if (row < M && col < M) {
            int c4s = c4 ^ (rl & 15);
            float4 v = *(const float4*)&smem[rl * 68 + (c4s << 2)];
            __builtin_nontemporal_store(*(const f32x4*)&v, (f32x4*)&C[(size_t)row * M + col]);
        }
    }
    // mirror write for strictly off-diagonal tiles: out rows J..J+63, cols I..I+127
    if (bj64 >= 2 * bi + 2) {
#pragma unroll
        for (int it = 0; it < 8; ++it) {
            int cl = it * 8 + (tid >> 5);
            int rbase = (tid & 31) * 4;
            int row = J + cl, col = I + rbase;
            if (row < M && col < M) {
                float vv[4];
#pragma unroll
                for (int k = 0; k < 4; ++k) {
                    int rr = rbase + k;
                    vv[k] = smem[rr * 68 + ((((cl >> 2) ^ (rr & 15))) << 2) + (cl & 3)];
                }
                float4 v = make_float4(vv[0], vv[1], vv[2], vv[3]);
                __builtin_nontemporal_store(*(const f32x4*)&v, (f32x4*)&C[(size_t)row * M + col]);
            }
        }
    }
    __syncthreads();
}

// ---------- phases ----------

__device__ void run_phase(int ph, const MegaArgs& A, float* smem) {
    int gtid = blockIdx.x * 256 + threadIdx.x;
    int gsz = gridDim.x * 256;
    int nt = A.Mpad / 128;
    switch (ph) {
    case 0: {   // cursor init + weight transpose/split
        for (int i = gtid; i < A.N; i += gsz) A.cursor[i] = 0;
        for (int idx = gtid; idx < WT_TOTAL; idx += gsz) {
            const float* src; int base, shK, Nc;
            if (idx < W2T_OFF)       { src = A.W1;  base = W1T_OFF;  shK = 10; Nc = 128; }
            else if (idx < Wa1T_OFF) { src = A.W2;  base = W2T_OFF;  shK = 7;  Nc = 64; }
            else if (idx < Wa2T_OFF) { src = A.Wa1; base = Wa1T_OFF; shK = 6;  Nc = 128; }
            else if (idx < WsT_OFF)  { src = A.Wa2; base = Wa2T_OFF; shK = 7;  Nc = 1024; }
            else                     { src = A.Ws;  base = WsT_OFF;  shK = 6;  Nc = 64; }
            int local = idx - base;
            int nn = local >> shK;
            int k = local & ((1 << shK) - 1);
            splitf(src[(size_t)k * Nc + nn], A.Whi[idx], A.Wlo[idx]);
        }
        break;
    }
    case 1: {   // fillpad + G1 (t128 = x @ W1)
        for (int e = gtid; e < A.E; e += gsz) {
            int s = A.ei[e], r = A.ei[A.E + e];
            int slot = atomicAdd(&A.cursor[r], 1);
            if (slot < DEGPAD) A.colPad[(size_t)r * DEGPAD + slot] = s;
        }
        for (int t = blockIdx.x; t < 2 * nt; t += gridDim.x)
            dev_gemm<1, false, false, false, false>(smem, t & 1, t >> 1,
                nullptr, nullptr, A.x, A.Whi + W1T_OFF, A.Wlo + W1T_OFF, nullptr,
                A.t128, nullptr, nullptr, A.N, 1024, 128);
        break;
    }
    case 2:
        dev_spmm<128, true, true, 1>(A.t128, A.colPad, A.cursor, A.b1, nullptr, A.Hhi, A.Hlo, A.N);
        break;
    case 3:
        for (int t = blockIdx.x; t < nt; t += gridDim.x)
            dev_gemm<0, false, false, false, false>(smem, 0, t,
                A.Hhi, A.Hlo, nullptr, A.Whi + W2T_OFF, A.Wlo + W2T_OFF, nullptr,
                A.t64, nullptr, nullptr, A.N, 128, 64);
        break;
    case 4:
        dev_spmm<64, true, true, 0>(A.t64, A.colPad, A.cursor, A.b2, A.zout, nullptr, nullptr, A.N);
        break;
    case 5:
        dev_spmm<64, false, false, 1>(A.zout, A.colPad, A.cursor, nullptr, nullptr, A.AZhi, A.AZlo, A.N);
        break;
    case 6: {   // G3 (a = relu(AZ@Wa1+ba1)) + G4 (S = relu(AZ@Ws+bs) -> split)
        int n3 = 2 * nt;
        for (int t = blockIdx.x; t < n3 + nt; t += gridDim.x) {
            if (t < n3)
                dev_gemm<0, true, true, false, false>(smem, t & 1, t >> 1,
                    A.AZhi, A.AZlo, nullptr, A.Whi + Wa1T_OFF, A.Wlo + Wa1T_OFF, A.ba1,
                    A.t128, nullptr, nullptr, A.N, 64, 128);
            else
                dev_gemm<0, true, true, true, false>(smem, 0, t - n3,
                    A.AZhi, A.AZlo, nullptr, A.Whi + WsT_OFF, A.Wlo + WsT_OFF, A.bs,
                    nullptr, A.Shi, A.Slo, A.N, 64, 64);
        }
        break;
    }
    case 7:
        dev_spmm<128, false, false, 1>(A.t128, A.colPad, A.cursor, nullptr, nullptr, A.AAhi, A.AAlo, A.N);
        break;
    case 8: {   // G5 (attr) + sst (struct) concurrently
        int nG5 = 16 * nt;
        int nSST = nt * (nt + 1);
        for (int t = blockIdx.x; t < nG5 + nSST; t += gridDim.x) {
            if (t < nG5)
                dev_gemm<0, true, true, false, true>(smem, t & 15, t >> 4,
                    A.AAhi, A.AAlo, nullptr, A.Whi + Wa2T_OFF, A.Wlo + Wa2T_OFF, A.ba2,
                    A.attr, nullptr, nullptr, A.N, 128, 1024);
            else {
                int tt = t - nG5;
                int bi = 0;
                while (tt >= 2 * (nt - bi)) { tt -= 2 * (nt - bi); bi++; }
                dev_sst(smem, bi, 2 * bi + tt, A.Shi, A.Slo, A.st, A.N);
            }
        }
        break;
    }
    }
}

__global__ __launch_bounds__(256, 2) void k_mega(MegaArgs A) {
    __shared__ float smem[128 * 68];
    for (int ph = A.ph_lo; ph <= A.ph_hi; ++ph) {
        run_phase(ph, A, smem);
        if (A.coop && ph != A.ph_hi) cooperative_groups::this_grid().sync();
    }
}

// ---------- launch ----------

extern "C" void kernel_launch(void* const* d_in, const int* in_sizes, int n_in,
                              void* d_out, int out_size, void* d_ws, size_t ws_size,
                              hipStream_t stream) {
    MegaArgs A;
    A.x   = (const float*)d_in[0];
    A.ei  = (const int*)d_in[1];
    A.W1  = (const float*)d_in[2];  A.b1  = (const float*)d_in[3];
    A.W2  = (const float*)d_in[4];  A.b2  = (const float*)d_in[5];
    A.Wa1 = (const float*)d_in[6];  A.ba1 = (const float*)d_in[7];
    A.Wa2 = (const float*)d_in[8];  A.ba2 = (const float*)d_in[9];
    A.Ws  = (const float*)d_in[10]; A.bs  = (const float*)d_in[11];

    A.N = in_sizes[0] / IN_DIM;
    A.E = in_sizes[1] / 2;
    A.Mpad = ((A.N + 127) / 128) * 128;

    float* out = (float*)d_out;
    A.attr = out;
    A.st   = out + (size_t)A.N * IN_DIM;
    A.zout = A.st + (size_t)A.N * A.N;

    char* basep = (char*)d_ws;
    size_t off = 0;
    auto alloc = [&](size_t bytes) -> void* {
        void* p = basep + off;
        off = (off + bytes + 255) & ~(size_t)255;
        return p;
    };
    A.colPad = (int*)alloc((size_t)A.N * DEGPAD * 4);
    A.cursor = (int*)alloc((size_t)A.N * 4);
    A.Whi = (__hip_bfloat16*)alloc((size_t)WT_TOTAL * 2);
    A.Wlo = (__hip_bfloat16*)alloc((size_t)WT_TOTAL * 2);
    A.t128 = (float*)alloc((size_t)A.N * 128 * 4);
    A.t64  = (float*)alloc((size_t)A.N * 64 * 4);
    A.Hhi  = (__hip_bfloat16*)alloc((size_t)A.Mpad * 128 * 2);
    A.Hlo  = (__hip_bfloat16*)alloc((size_t)A.Mpad * 128 * 2);
    A.AZhi = (__hip_bfloat16*)alloc((size_t)A.Mpad * 64 * 2);
    A.AZlo = (__hip_bfloat16*)alloc((size_t)A.Mpad * 64 * 2);
    A.AAhi = (__hip_bfloat16*)alloc((size_t)A.Mpad * 128 * 2);
    A.AAlo = (__hip_bfloat16*)alloc((size_t)A.Mpad * 128 * 2);
    A.Shi  = (__hip_bfloat16*)alloc((size_t)A.Mpad * 64 * 2);
    A.Slo  = (__hip_bfloat16*)alloc((size_t)A.Mpad * 64 * 2);

    int dev = 0;
    hipGetDevice(&dev);
    int ncu = 256;
    hipDeviceGetAttribute(&ncu, hipDeviceAttributeMultiprocessorCount, dev);
    int maxb = 0;
    hipOccupancyMaxActiveBlocksPerMultiprocessor(&maxb, k_mega, 256, 0);
    if (maxb < 1) maxb = 1;
    int grid = ncu * maxb;

    A.coop = 1; A.ph_lo = 0; A.ph_hi = 8;
    void* kargs[] = { (void*)&A };
    hipError_t err = hipLaunchCooperativeKernel((const void*)k_mega, dim3(grid), dim3(256),
                                                kargs, 0, stream);
    if (err != hipSuccess) {
        // fallback: one normal launch per phase (stream order provides the sync)
        for (int p = 0; p <= 8; ++p) {
            MegaArgs B = A;
            B.coop = 0; B.ph_lo = B.ph_hi = p;
            k_mega<<<dim3(grid), dim3(256), 0, stream>>>(B);
        }
    }
}

// Round 7
// 399.190 us; speedup vs baseline: 2.5312x; 2.5312x over previous
//
#include <hip/hip_runtime.h>
#include <hip/hip_bf16.h>

#define IN_DIM 1024
#define HID 128
#define LAT 64
#define DEGPAD 128

typedef __attribute__((ext_vector_type(8))) short bf16x8;
typedef __attribute__((ext_vector_type(4))) short bf16x4;
typedef __attribute__((ext_vector_type(4))) float f32x4;

// weight-transpose-split arena offsets (bf16 elements)
#define W1T_OFF 0
#define W2T_OFF 131072
#define Wa1T_OFF 139264
#define Wa2T_OFF 147456
#define WsT_OFF 278528
#define WT_TOTAL 282624

__device__ __forceinline__ void splitf(float v, __hip_bfloat16& h, __hip_bfloat16& l) {
    h = __float2bfloat16(v);
    l = __float2bfloat16(v - __bfloat162float(h));
}

// ---------- dense GEMM tile (block tile 128x64, 4 waves 2x2, wave tile 64x32) ----------
// AMODE 0: A as hi/lo bf16 (rows < Mpad valid); AMODE 1: A fp32 row-guarded, in-reg split.
// C[row*ldc + col], row < M; CGUARD adds col < ncol (ncol % 4 == 0).

template<int AMODE, bool BIAS, bool RELU, bool SPLITOUT, bool NT, bool CGUARD>
__device__ void dev_gemm(float* smem, int bx, int byy,
        const __hip_bfloat16* __restrict__ Ahi, const __hip_bfloat16* __restrict__ Alo,
        const float* __restrict__ Af,
        const __hip_bfloat16* __restrict__ Bthi, const __hip_bfloat16* __restrict__ Btlo,
        const float* __restrict__ bias,
        float* __restrict__ Cf, __hip_bfloat16* __restrict__ Chi, __hip_bfloat16* __restrict__ Clo,
        int M, int K, int ldc, int ncol) {
    int tid = threadIdx.x;
    int w = tid >> 6, lane = tid & 63;
    int wr = w >> 1, wc = w & 1;
    int m0 = byy * 128, n0 = bx * 64;
    int lrow = lane & 15, lk = (lane >> 4) * 8;

    int arow[4];
    size_t aoff[4];
#pragma unroll
    for (int mi = 0; mi < 4; ++mi) {
        arow[mi] = m0 + wr * 64 + mi * 16 + lrow;
        aoff[mi] = (size_t)arow[mi] * K + lk;
    }
    size_t boff[2];
#pragma unroll
    for (int nj = 0; nj < 2; ++nj)
        boff[nj] = (size_t)(n0 + wc * 32 + nj * 16 + lrow) * K + lk;

    f32x4 acc[4][2] = {};

    for (int k0 = 0; k0 < K; k0 += 32) {
        bf16x8 bh[2], bl[2], ah[4], al[4];
#pragma unroll
        for (int nj = 0; nj < 2; ++nj) {
            bh[nj] = *(const bf16x8*)(Bthi + boff[nj] + k0);
            bl[nj] = *(const bf16x8*)(Btlo + boff[nj] + k0);
        }
        if constexpr (AMODE == 0) {
#pragma unroll
            for (int mi = 0; mi < 4; ++mi) {
                ah[mi] = *(const bf16x8*)(Ahi + aoff[mi] + k0);
                al[mi] = *(const bf16x8*)(Alo + aoff[mi] + k0);
            }
        } else {
#pragma unroll
            for (int mi = 0; mi < 4; ++mi) {
                float4 f0 = make_float4(0.f, 0.f, 0.f, 0.f), f1 = f0;
                if (arow[mi] < M) {
                    f0 = *(const float4*)(Af + aoff[mi] + k0);
                    f1 = *(const float4*)(Af + aoff[mi] + k0 + 4);
                }
                float ff[8] = {f0.x, f0.y, f0.z, f0.w, f1.x, f1.y, f1.z, f1.w};
                __attribute__((aligned(16))) __hip_bfloat16 hb[8], lb[8];
#pragma unroll
                for (int t = 0; t < 8; ++t) splitf(ff[t], hb[t], lb[t]);
                ah[mi] = *(const bf16x8*)hb;
                al[mi] = *(const bf16x8*)lb;
            }
        }
#pragma unroll
        for (int mi = 0; mi < 4; ++mi)
#pragma unroll
            for (int nj = 0; nj < 2; ++nj) {
                acc[mi][nj] = __builtin_amdgcn_mfma_f32_16x16x32_bf16(ah[mi], bh[nj], acc[mi][nj], 0, 0, 0);
                acc[mi][nj] = __builtin_amdgcn_mfma_f32_16x16x32_bf16(ah[mi], bl[nj], acc[mi][nj], 0, 0, 0);
                acc[mi][nj] = __builtin_amdgcn_mfma_f32_16x16x32_bf16(al[mi], bh[nj], acc[mi][nj], 0, 0, 0);
            }
    }

    // stage to LDS, stride 68 (no xor): stage = 2-way (free), row-read = uniform banks
    int r0 = (lane >> 4) * 4;
#pragma unroll
    for (int mi = 0; mi < 4; ++mi)
#pragma unroll
        for (int nj = 0; nj < 2; ++nj) {
            int cl = wc * 32 + nj * 16 + lrow;
#pragma unroll
            for (int r = 0; r < 4; ++r) {
                int rl = wr * 64 + mi * 16 + r0 + r;
                smem[rl * 68 + cl] = acc[mi][nj][r];
            }
        }
    __syncthreads();

#pragma unroll
    for (int it = 0; it < 8; ++it) {
        int rl = it * 16 + (tid >> 4);
        int c4 = tid & 15;
        int row = m0 + rl;
        int col = n0 + c4 * 4;
        bool ok = (row < M) && (!CGUARD || col < ncol);
        if (ok) {
            float4 v = *(const float4*)&smem[rl * 68 + c4 * 4];
            if (BIAS) {
                float4 b = *(const float4*)&bias[col];
                v.x += b.x; v.y += b.y; v.z += b.z; v.w += b.w;
            }
            if (RELU) {
                v.x = fmaxf(v.x, 0.f); v.y = fmaxf(v.y, 0.f);
                v.z = fmaxf(v.z, 0.f); v.w = fmaxf(v.w, 0.f);
            }
            if constexpr (SPLITOUT) {
                float vv[4] = {v.x, v.y, v.z, v.w};
                __attribute__((aligned(8))) __hip_bfloat16 hs[4], ls[4];
#pragma unroll
                for (int k = 0; k < 4; ++k) splitf(vv[k], hs[k], ls[k]);
                *(bf16x4*)&Chi[(size_t)row * ldc + col] = *(bf16x4*)hs;
                *(bf16x4*)&Clo[(size_t)row * ldc + col] = *(bf16x4*)ls;
            } else if constexpr (NT) {
                __builtin_nontemporal_store(*(const f32x4*)&v, (f32x4*)&Cf[(size_t)row * ldc + col]);
            } else {
                *(float4*)&Cf[(size_t)row * ldc + col] = v;
            }
        }
    }
    __syncthreads();
}

// ---------- kernels ----------

// prep: cursor = 0, weight transpose+split
__global__ __launch_bounds__(256) void k_prep(const float* __restrict__ W1, const float* __restrict__ W2,
                                              const float* __restrict__ Wa1, const float* __restrict__ Wa2,
                                              const float* __restrict__ Ws,
                                              __hip_bfloat16* __restrict__ hi, __hip_bfloat16* __restrict__ lo,
                                              int* cursor, int N) {
    int gtid = blockIdx.x * 256 + threadIdx.x;
    int gsz = gridDim.x * 256;
    for (int i = gtid; i < N; i += gsz) cursor[i] = 0;
    for (int idx = gtid; idx < WT_TOTAL; idx += gsz) {
        const float* src; int base, shK, Nc;
        if (idx < W2T_OFF)       { src = W1;  base = W1T_OFF;  shK = 10; Nc = 128; }
        else if (idx < Wa1T_OFF) { src = W2;  base = W2T_OFF;  shK = 7;  Nc = 64; }
        else if (idx < Wa2T_OFF) { src = Wa1; base = Wa1T_OFF; shK = 6;  Nc = 128; }
        else if (idx < WsT_OFF)  { src = Wa2; base = Wa2T_OFF; shK = 7;  Nc = 1024; }
        else                     { src = Ws;  base = WsT_OFF;  shK = 6;  Nc = 64; }
        int local = idx - base;
        int nn = local >> shK;
        int k = local & ((1 << shK) - 1);
        splitf(src[(size_t)k * Nc + nn], hi[idx], lo[idx]);
    }
}

// build: edge fill (atomics) + G1 (t128 = x @ W1, fp32 A in-reg split)
__global__ __launch_bounds__(256) void k_build(const int* __restrict__ ei, int* cursor,
                                               int* __restrict__ colPad, int E,
                                               const float* __restrict__ x,
                                               const __hip_bfloat16* __restrict__ Whi,
                                               const __hip_bfloat16* __restrict__ Wlo,
                                               float* __restrict__ t128, int M, int Mpad) {
    __shared__ float smem[128 * 68];
    int gtid = blockIdx.x * 256 + threadIdx.x;
    int gsz = gridDim.x * 256;
    for (int e = gtid; e < E; e += gsz) {
        int s = ei[e], r = ei[E + e];
        int slot = atomicAdd(&cursor[r], 1);
        if (slot < DEGPAD) colPad[(size_t)r * DEGPAD + slot] = s;
    }
    int nt2 = (Mpad / 128) * 2;
    for (int t = blockIdx.x; t < nt2; t += gridDim.x)
        dev_gemm<1, false, false, false, false, false>(smem, t & 1, t >> 1,
            nullptr, nullptr, x, Whi + W1T_OFF, Wlo + W1T_OFF, nullptr,
            t128, nullptr, nullptr, M, 1024, 128, 0);
}

// SpMM (one wave per row), dis on the fly from cursor. OMODE 0: fp32; 1: split bf16.
template<int F, bool BIAS, bool RELU, int OMODE>
__global__ __launch_bounds__(256) void k_spmm(const float* __restrict__ Hin,
                                              const int* __restrict__ colPad,
                                              const int* __restrict__ cursor,
                                              const float* __restrict__ bias,
                                              float* __restrict__ out,
                                              __hip_bfloat16* __restrict__ ohi,
                                              __hip_bfloat16* __restrict__ olo, int n) {
    int i = (blockIdx.x * 256 + threadIdx.x) >> 6;
    int lane = threadIdx.x & 63;
    if (i >= n) return;
    int d = cursor[i];
    float di = rsqrtf((float)(d + 1));
    if (d > DEGPAD) d = DEGPAD;
    const int* cp = colPad + (size_t)i * DEGPAD;
    float acc[F / 64];
    const float* self = Hin + (size_t)i * F;
#pragma unroll
    for (int j = 0; j < F / 64; ++j) acc[j] = di * self[lane + 64 * j];
    for (int p = 0; p < d; ++p) {
        int c = cp[p];
        float dc = rsqrtf((float)(cursor[c] + 1));
        const float* row = Hin + (size_t)c * F;
#pragma unroll
        for (int j = 0; j < F / 64; ++j) acc[j] = fmaf(dc, row[lane + 64 * j], acc[j]);
    }
#pragma unroll
    for (int j = 0; j < F / 64; ++j) {
        float r = acc[j] * di;
        if (BIAS) r += bias[lane + 64 * j];
        if (RELU) r = fmaxf(r, 0.f);
        size_t idx = (size_t)i * F + lane + 64 * j;
        if constexpr (OMODE == 1) {
            __hip_bfloat16 h, l;
            splitf(r, h, l);
            ohi[idx] = h; olo[idx] = l;
        } else {
            out[idx] = r;
        }
    }
}

// G2: t64 = H @ W2
__global__ __launch_bounds__(256) void k_g2(const __hip_bfloat16* __restrict__ Hhi,
                                            const __hip_bfloat16* __restrict__ Hlo,
                                            const __hip_bfloat16* __restrict__ Whi,
                                            const __hip_bfloat16* __restrict__ Wlo,
                                            float* __restrict__ t64, int M) {
    __shared__ float smem[128 * 68];
    dev_gemm<0, false, false, false, false, false>(smem, 0, blockIdx.x,
        Hhi, Hlo, nullptr, Whi + W2T_OFF, Wlo + W2T_OFF, nullptr,
        t64, nullptr, nullptr, M, 128, 64, 0);
}

// G3 + G4 (both consume AZ)
__global__ __launch_bounds__(256) void k_g34(const __hip_bfloat16* __restrict__ AZhi,
                                             const __hip_bfloat16* __restrict__ AZlo,
                                             const __hip_bfloat16* __restrict__ Whi,
                                             const __hip_bfloat16* __restrict__ Wlo,
                                             const float* __restrict__ ba1, const float* __restrict__ bs,
                                             float* __restrict__ t128,
                                             __hip_bfloat16* __restrict__ Shi, __hip_bfloat16* __restrict__ Slo,
                                             int M, int Mpad) {
    __shared__ float smem[128 * 68];
    int nt2 = (Mpad / 128) * 2;
    int t = blockIdx.x;
    if (t < nt2)
        dev_gemm<0, true, true, false, false, false>(smem, t & 1, t >> 1,
            AZhi, AZlo, nullptr, Whi + Wa1T_OFF, Wlo + Wa1T_OFF, ba1,
            t128, nullptr, nullptr, M, 64, 128, 0);
    else
        dev_gemm<0, true, true, true, false, false>(smem, 0, t - nt2,
            AZhi, AZlo, nullptr, Whi + WsT_OFF, Wlo + WsT_OFF, bs,
            nullptr, Shi, Slo, M, 64, 64, 0);
}

// tail: G5 (attr, NT) + full sst (all 128x64 half-tiles, no mirror, NT)
__global__ __launch_bounds__(256) void k_tail(const __hip_bfloat16* __restrict__ AAhi,
                                              const __hip_bfloat16* __restrict__ AAlo,
                                              const __hip_bfloat16* __restrict__ Whi,
                                              const __hip_bfloat16* __restrict__ Wlo,
                                              const float* __restrict__ ba2,
                                              const __hip_bfloat16* __restrict__ Shi,
                                              const __hip_bfloat16* __restrict__ Slo,
                                              float* __restrict__ attr, float* __restrict__ st,
                                              int M, int Mpad) {
    __shared__ float smem[128 * 68];
    int nt = Mpad / 128;
    int nG5 = 16 * nt;
    int t = blockIdx.x;
    if (t < nG5) {
        dev_gemm<0, true, true, false, true, false>(smem, t & 15, t >> 4,
            AAhi, AAlo, nullptr, Whi + Wa2T_OFF, Wlo + Wa2T_OFF, ba2,
            attr, nullptr, nullptr, M, 128, 1024, 0);
    } else {
        int tt = t - nG5;
        int nt2 = 2 * nt;
        int bi = tt / nt2, bj = tt - bi * nt2;
        dev_gemm<0, false, false, false, true, true>(smem, bj, bi,
            Shi, Slo, nullptr, Shi, Slo, nullptr,
            st, nullptr, nullptr, M, 64, M, M);
    }
}

// ---------- launch ----------

extern "C" void kernel_launch(void* const* d_in, const int* in_sizes, int n_in,
                              void* d_out, int out_size, void* d_ws, size_t ws_size,
                              hipStream_t stream) {
    const float* x   = (const float*)d_in[0];
    const int*   ei  = (const int*)d_in[1];
    const float* W1  = (const float*)d_in[2];
    const float* b1  = (const float*)d_in[3];
    const float* W2  = (const float*)d_in[4];
    const float* b2  = (const float*)d_in[5];
    const float* Wa1 = (const float*)d_in[6];
    const float* ba1 = (const float*)d_in[7];
    const float* Wa2 = (const float*)d_in[8];
    const float* ba2 = (const float*)d_in[9];
    const float* Ws  = (const float*)d_in[10];
    const float* bs  = (const float*)d_in[11];

    int N = in_sizes[0] / IN_DIM;
    int E = in_sizes[1] / 2;
    int Mpad = ((N + 127) / 128) * 128;
    int nt = Mpad / 128;

    float* out  = (float*)d_out;
    float* attr = out;
    float* st   = out + (size_t)N * IN_DIM;
    float* zout = st + (size_t)N * N;

    char* basep = (char*)d_ws;
    size_t off = 0;
    auto alloc = [&](size_t bytes) -> void* {
        void* p = basep + off;
        off = (off + bytes + 255) & ~(size_t)255;
        return p;
    };
    int*   colPad = (int*)alloc((size_t)N * DEGPAD * 4);
    int*   cursor = (int*)alloc((size_t)N * 4);
    __hip_bfloat16* Whi = (__hip_bfloat16*)alloc((size_t)WT_TOTAL * 2);
    __hip_bfloat16* Wlo = (__hip_bfloat16*)alloc((size_t)WT_TOTAL * 2);
    float* t128 = (float*)alloc((size_t)N * 128 * 4);
    float* t64  = (float*)alloc((size_t)N * 64 * 4);
    __hip_bfloat16* Hhi  = (__hip_bfloat16*)alloc((size_t)Mpad * 128 * 2);
    __hip_bfloat16* Hlo  = (__hip_bfloat16*)alloc((size_t)Mpad * 128 * 2);
    __hip_bfloat16* AZhi = (__hip_bfloat16*)alloc((size_t)Mpad * 64 * 2);
    __hip_bfloat16* AZlo = (__hip_bfloat16*)alloc((size_t)Mpad * 64 * 2);
    __hip_bfloat16* AAhi = (__hip_bfloat16*)alloc((size_t)Mpad * 128 * 2);
    __hip_bfloat16* AAlo = (__hip_bfloat16*)alloc((size_t)Mpad * 128 * 2);
    __hip_bfloat16* Shi  = (__hip_bfloat16*)alloc((size_t)Mpad * 64 * 2);
    __hip_bfloat16* Slo  = (__hip_bfloat16*)alloc((size_t)Mpad * 64 * 2);

    dim3 b256(256);
    int spmm_grid = (N * 64 + 255) / 256;

    // 1. prep (cursor zero + weight split)
    k_prep<<<dim3(1104), b256, 0, stream>>>(W1, W2, Wa1, Wa2, Ws, Whi, Wlo, cursor, N);
    // 2. build (edge fill + G1)
    k_build<<<dim3(1280), b256, 0, stream>>>(ei, cursor, colPad, E, x, Whi, Wlo, t128, N, Mpad);
    // 3. spmm1: H = relu(dis-norm prop(t128) + b1) -> split
    k_spmm<128, true, true, 1><<<dim3(spmm_grid), b256, 0, stream>>>(
        t128, colPad, cursor, b1, nullptr, Hhi, Hlo, N);
    // 4. G2: t64 = H @ W2
    k_g2<<<dim3(nt), b256, 0, stream>>>(Hhi, Hlo, Whi, Wlo, t64, N);
    // 5. spmm2: z = relu(prop(t64) + b2) -> zout (fp32 output)
    k_spmm<64, true, true, 0><<<dim3(spmm_grid), b256, 0, stream>>>(
        t64, colPad, cursor, b2, zout, nullptr, nullptr, N);
    // 6. spmm3: AZ = prop(zout) -> split
    k_spmm<64, false, false, 1><<<dim3(spmm_grid), b256, 0, stream>>>(
        zout, colPad, cursor, nullptr, nullptr, AZhi, AZlo, N);
    // 7. G3 + G4
    k_g34<<<dim3(3 * nt), b256, 0, stream>>>(AZhi, AZlo, Whi, Wlo, ba1, bs, t128, Shi, Slo, N, Mpad);
    // 8. spmm4: AA = prop(t128) -> split
    k_spmm<128, false, false, 1><<<dim3(spmm_grid), b256, 0, stream>>>(
        t128, colPad, cursor, nullptr, nullptr, AAhi, AAlo, N);
    // 9. tail: G5 (attr) + sst (struct)
    k_tail<<<dim3(16 * nt + nt * 2 * nt), b256, 0, stream>>>(
        AAhi, AAlo, Whi, Wlo, ba2, Shi, Slo, attr, st, N, Mpad);
}

// Round 8
// 365.173 us; speedup vs baseline: 2.7669x; 1.0932x over previous
//
#include <hip/hip_runtime.h>
#include <hip/hip_bf16.h>

#define IN_DIM 1024
#define HID 128
#define LAT 64
#define DEGPAD 128

typedef __attribute__((ext_vector_type(8))) short bf16x8;
typedef __attribute__((ext_vector_type(4))) short bf16x4;
typedef __attribute__((ext_vector_type(4))) float f32x4;

// weight-transpose-split arena offsets (bf16 elements)
#define W1T_OFF 0
#define W2T_OFF 131072
#define Wa1T_OFF 139264
#define Wa2T_OFF 147456
#define WsT_OFF 278528
#define WT_TOTAL 282624

__device__ __forceinline__ void splitf(float v, __hip_bfloat16& h, __hip_bfloat16& l) {
    h = __float2bfloat16(v);
    l = __float2bfloat16(v - __bfloat162float(h));
}

// ---------- dense GEMM tile (block tile 128x64, 4 waves 2x2, wave tile 64x32) ----------
// AMODE 0: A as hi/lo bf16 (rows < Mpad valid memory); AMODE 1: A fp32 row-guarded, in-reg split.
// Epilogue: +bias, relu, then *rsqrt(cursor[row]+1) if DIS (pre-scale for next SpMM).

template<int AMODE, bool BIAS, bool RELU, bool DIS, bool SPLITOUT, bool NT>
__device__ void dev_gemm(float* smem, int bx, int byy,
        const __hip_bfloat16* __restrict__ Ahi, const __hip_bfloat16* __restrict__ Alo,
        const float* __restrict__ Af,
        const __hip_bfloat16* __restrict__ Bthi, const __hip_bfloat16* __restrict__ Btlo,
        const float* __restrict__ bias, const int* __restrict__ cursor,
        float* __restrict__ Cf, __hip_bfloat16* __restrict__ Chi, __hip_bfloat16* __restrict__ Clo,
        int M, int K, int ldc) {
    int tid = threadIdx.x;
    int w = tid >> 6, lane = tid & 63;
    int wr = w >> 1, wc = w & 1;
    int m0 = byy * 128, n0 = bx * 64;
    int lrow = lane & 15, lk = (lane >> 4) * 8;

    int arow[4];
    size_t aoff[4];
#pragma unroll
    for (int mi = 0; mi < 4; ++mi) {
        arow[mi] = m0 + wr * 64 + mi * 16 + lrow;
        aoff[mi] = (size_t)arow[mi] * K + lk;
    }
    size_t boff[2];
#pragma unroll
    for (int nj = 0; nj < 2; ++nj)
        boff[nj] = (size_t)(n0 + wc * 32 + nj * 16 + lrow) * K + lk;

    f32x4 acc[4][2] = {};

    for (int k0 = 0; k0 < K; k0 += 32) {
        bf16x8 bh[2], bl[2], ah[4], al[4];
#pragma unroll
        for (int nj = 0; nj < 2; ++nj) {
            bh[nj] = *(const bf16x8*)(Bthi + boff[nj] + k0);
            bl[nj] = *(const bf16x8*)(Btlo + boff[nj] + k0);
        }
        if constexpr (AMODE == 0) {
#pragma unroll
            for (int mi = 0; mi < 4; ++mi) {
                ah[mi] = *(const bf16x8*)(Ahi + aoff[mi] + k0);
                al[mi] = *(const bf16x8*)(Alo + aoff[mi] + k0);
            }
        } else {
#pragma unroll
            for (int mi = 0; mi < 4; ++mi) {
                float4 f0 = make_float4(0.f, 0.f, 0.f, 0.f), f1 = f0;
                if (arow[mi] < M) {
                    f0 = *(const float4*)(Af + aoff[mi] + k0);
                    f1 = *(const float4*)(Af + aoff[mi] + k0 + 4);
                }
                float ff[8] = {f0.x, f0.y, f0.z, f0.w, f1.x, f1.y, f1.z, f1.w};
                __attribute__((aligned(16))) __hip_bfloat16 hb[8], lb[8];
#pragma unroll
                for (int t = 0; t < 8; ++t) splitf(ff[t], hb[t], lb[t]);
                ah[mi] = *(const bf16x8*)hb;
                al[mi] = *(const bf16x8*)lb;
            }
        }
#pragma unroll
        for (int mi = 0; mi < 4; ++mi)
#pragma unroll
            for (int nj = 0; nj < 2; ++nj) {
                acc[mi][nj] = __builtin_amdgcn_mfma_f32_16x16x32_bf16(ah[mi], bh[nj], acc[mi][nj], 0, 0, 0);
                acc[mi][nj] = __builtin_amdgcn_mfma_f32_16x16x32_bf16(ah[mi], bl[nj], acc[mi][nj], 0, 0, 0);
                acc[mi][nj] = __builtin_amdgcn_mfma_f32_16x16x32_bf16(al[mi], bh[nj], acc[mi][nj], 0, 0, 0);
            }
    }

    // stage to LDS, stride 68 (2-way banks on stage and read — free)
    int r0 = (lane >> 4) * 4;
#pragma unroll
    for (int mi = 0; mi < 4; ++mi)
#pragma unroll
        for (int nj = 0; nj < 2; ++nj) {
            int cl = wc * 32 + nj * 16 + lrow;
#pragma unroll
            for (int r = 0; r < 4; ++r) {
                int rl = wr * 64 + mi * 16 + r0 + r;
                smem[rl * 68 + cl] = acc[mi][nj][r];
            }
        }
    __syncthreads();

#pragma unroll
    for (int it = 0; it < 8; ++it) {
        int rl = it * 16 + (tid >> 4);
        int c4 = tid & 15;
        int row = m0 + rl;
        if (row < M) {
            int col = n0 + c4 * 4;
            float4 v = *(const float4*)&smem[rl * 68 + c4 * 4];
            if (BIAS) {
                float4 b = *(const float4*)&bias[col];
                v.x += b.x; v.y += b.y; v.z += b.z; v.w += b.w;
            }
            if (RELU) {
                v.x = fmaxf(v.x, 0.f); v.y = fmaxf(v.y, 0.f);
                v.z = fmaxf(v.z, 0.f); v.w = fmaxf(v.w, 0.f);
            }
            if (DIS) {
                float di = rsqrtf((float)(cursor[row] + 1));
                v.x *= di; v.y *= di; v.z *= di; v.w *= di;
            }
            if constexpr (SPLITOUT) {
                float vv[4] = {v.x, v.y, v.z, v.w};
                __attribute__((aligned(8))) __hip_bfloat16 hs[4], ls[4];
#pragma unroll
                for (int k = 0; k < 4; ++k) splitf(vv[k], hs[k], ls[k]);
                *(bf16x4*)&Chi[(size_t)row * ldc + col] = *(bf16x4*)hs;
                *(bf16x4*)&Clo[(size_t)row * ldc + col] = *(bf16x4*)ls;
            } else if constexpr (NT) {
                __builtin_nontemporal_store(*(const f32x4*)&v, (f32x4*)&Cf[(size_t)row * ldc + col]);
            } else {
                *(float4*)&Cf[(size_t)row * ldc + col] = v;
            }
        }
    }
    __syncthreads();
}

// ---------- sst 128x128 tile, upper triangle; mirror written DIRECT from acc (float4, full lines) ----------

__device__ void dev_sst(float* smem, int bi, int bj,
                        const __hip_bfloat16* __restrict__ Shi, const __hip_bfloat16* __restrict__ Slo,
                        float* __restrict__ C, int M) {
    int tid = threadIdx.x;
    int w = tid >> 6, lane = tid & 63;
    int wr = w >> 1, wc = w & 1;
    int i0 = bi * 128 + wr * 64;
    int j0 = bj * 128 + wc * 64;
    int lrow = lane & 15, lk = (lane >> 4) * 8;

    f32x4 acc[4][4] = {};
#pragma unroll
    for (int ks = 0; ks < 2; ++ks) {
        bf16x8 ah[4], al[4], bh[4], bl[4];
#pragma unroll
        for (int mi = 0; mi < 4; ++mi) {
            size_t off = (size_t)(i0 + mi * 16 + lrow) * 64 + ks * 32 + lk;
            ah[mi] = *(const bf16x8*)(Shi + off);
            al[mi] = *(const bf16x8*)(Slo + off);
        }
#pragma unroll
        for (int nj = 0; nj < 4; ++nj) {
            size_t off = (size_t)(j0 + nj * 16 + lrow) * 64 + ks * 32 + lk;
            bh[nj] = *(const bf16x8*)(Shi + off);
            bl[nj] = *(const bf16x8*)(Slo + off);
        }
#pragma unroll
        for (int mi = 0; mi < 4; ++mi)
#pragma unroll
            for (int nj = 0; nj < 4; ++nj) {
                acc[mi][nj] = __builtin_amdgcn_mfma_f32_16x16x32_bf16(ah[mi], bh[nj], acc[mi][nj], 0, 0, 0);
                acc[mi][nj] = __builtin_amdgcn_mfma_f32_16x16x32_bf16(ah[mi], bl[nj], acc[mi][nj], 0, 0, 0);
                acc[mi][nj] = __builtin_amdgcn_mfma_f32_16x16x32_bf16(al[mi], bh[nj], acc[mi][nj], 0, 0, 0);
            }
    }

    int r0 = (lane >> 4) * 4;

    // mirror write (C symmetric): acc[mi][nj] = 4 consecutive rows of one col
    // -> 4 consecutive cols of the mirrored tile -> direct float4, 16 rows x 64B lines per instr
    if (bi != bj) {
#pragma unroll
        for (int mi = 0; mi < 4; ++mi)
#pragma unroll
            for (int nj = 0; nj < 4; ++nj) {
                int orow = j0 + nj * 16 + lrow;       // mirrored out row
                int ocol = i0 + mi * 16 + r0;         // mirrored out col (x4)
                if (orow < M && ocol < M) {
                    f32x4 v = acc[mi][nj];
                    __builtin_nontemporal_store(v, (f32x4*)&C[(size_t)orow * M + ocol]);
                }
            }
    }

    // normal write via LDS transpose, two 64-col passes (34KB)
#pragma unroll
    for (int p = 0; p < 2; ++p) {
        if (wc == p) {
#pragma unroll
            for (int mi = 0; mi < 4; ++mi)
#pragma unroll
                for (int nj = 0; nj < 4; ++nj) {
                    int cl = nj * 16 + lrow;
#pragma unroll
                    for (int r = 0; r < 4; ++r) {
                        int rl = wr * 64 + mi * 16 + r0 + r;
                        smem[rl * 68 + cl] = acc[mi][nj][r];
                    }
                }
        }
        __syncthreads();
#pragma unroll
        for (int it = 0; it < 8; ++it) {
            int rl = it * 16 + (tid >> 4);
            int c4 = tid & 15;
            int row = bi * 128 + rl;
            int col = bj * 128 + p * 64 + c4 * 4;
            if (row < M && col < M) {
                float4 v = *(const float4*)&smem[rl * 68 + c4 * 4];
                __builtin_nontemporal_store(*(const f32x4*)&v, (f32x4*)&C[(size_t)row * M + col]);
            }
        }
        __syncthreads();
    }
}

// ---------- kernels ----------

// prep: cursor = 0, weight transpose+split
__global__ __launch_bounds__(256) void k_prep(const float* __restrict__ W1, const float* __restrict__ W2,
                                              const float* __restrict__ Wa1, const float* __restrict__ Wa2,
                                              const float* __restrict__ Ws,
                                              __hip_bfloat16* __restrict__ hi, __hip_bfloat16* __restrict__ lo,
                                              int* cursor, int N) {
    int gtid = blockIdx.x * 256 + threadIdx.x;
    int gsz = gridDim.x * 256;
    for (int i = gtid; i < N; i += gsz) cursor[i] = 0;
    for (int idx = gtid; idx < WT_TOTAL; idx += gsz) {
        const float* src; int base, shK, Nc;
        if (idx < W2T_OFF)       { src = W1;  base = W1T_OFF;  shK = 10; Nc = 128; }
        else if (idx < Wa1T_OFF) { src = W2;  base = W2T_OFF;  shK = 7;  Nc = 64; }
        else if (idx < Wa2T_OFF) { src = Wa1; base = Wa1T_OFF; shK = 6;  Nc = 128; }
        else if (idx < WsT_OFF)  { src = Wa2; base = Wa2T_OFF; shK = 7;  Nc = 1024; }
        else                     { src = Ws;  base = WsT_OFF;  shK = 6;  Nc = 64; }
        int local = idx - base;
        int nn = local >> shK;
        int k = local & ((1 << shK) - 1);
        splitf(src[(size_t)k * Nc + nn], hi[idx], lo[idx]);
    }
}

// build: edge fill (atomics) + G1 (t128 = x @ W1, unscaled — cursor not final here)
__global__ __launch_bounds__(256) void k_build(const int* __restrict__ ei, int* cursor,
                                               int* __restrict__ colPad, int E,
                                               const float* __restrict__ x,
                                               const __hip_bfloat16* __restrict__ Whi,
                                               const __hip_bfloat16* __restrict__ Wlo,
                                               float* __restrict__ t128, int M, int Mpad) {
    __shared__ float smem[128 * 68];
    int gtid = blockIdx.x * 256 + threadIdx.x;
    int gsz = gridDim.x * 256;
    for (int e = gtid; e < E; e += gsz) {
        int s = ei[e], r = ei[E + e];
        int slot = atomicAdd(&cursor[r], 1);
        if (slot < DEGPAD) colPad[(size_t)r * DEGPAD + slot] = s;
    }
    int nt2 = (Mpad / 128) * 2;
    for (int t = blockIdx.x; t < nt2; t += gridDim.x)
        dev_gemm<1, false, false, false, false, false>(smem, t & 1, t >> 1,
            nullptr, nullptr, x, Whi + W1T_OFF, Wlo + W1T_OFF, nullptr, nullptr,
            t128, nullptr, nullptr, M, 1024, 128);
}

// SpMM. GD: per-neighbor dc=rsqrt(cursor[c]+1) gather (input unscaled);
// else input pre-scaled by producer. OMODE 0: fp32; 1: split bf16; 2: fp32 + prescaled copy.
template<int F, bool BIAS, bool RELU, int OMODE, bool GD>
__global__ __launch_bounds__(256) void k_spmm(const float* __restrict__ Hin,
                                              const int* __restrict__ colPad,
                                              const int* __restrict__ cursor,
                                              const float* __restrict__ bias,
                                              float* __restrict__ out, float* __restrict__ out2,
                                              __hip_bfloat16* __restrict__ ohi,
                                              __hip_bfloat16* __restrict__ olo, int n) {
    int i = (blockIdx.x * 256 + threadIdx.x) >> 6;
    int lane = threadIdx.x & 63;
    if (i >= n) return;
    int d = cursor[i];
    float di = rsqrtf((float)(d + 1));
    if (d > DEGPAD) d = DEGPAD;
    const int* cp = colPad + (size_t)i * DEGPAD;
    float acc[F / 64];
    const float* self = Hin + (size_t)i * F;
#pragma unroll
    for (int j = 0; j < F / 64; ++j) acc[j] = (GD ? di : 1.f) * self[lane + 64 * j];
    for (int p = 0; p < d; ++p) {
        int c = cp[p];
        const float* row = Hin + (size_t)c * F;
        if constexpr (GD) {
            float dc = rsqrtf((float)(cursor[c] + 1));
#pragma unroll
            for (int j = 0; j < F / 64; ++j) acc[j] = fmaf(dc, row[lane + 64 * j], acc[j]);
        } else {
#pragma unroll
            for (int j = 0; j < F / 64; ++j) acc[j] += row[lane + 64 * j];
        }
    }
#pragma unroll
    for (int j = 0; j < F / 64; ++j) {
        float r = acc[j] * di;
        if (BIAS) r += bias[lane + 64 * j];
        if (RELU) r = fmaxf(r, 0.f);
        size_t idx = (size_t)i * F + lane + 64 * j;
        if constexpr (OMODE == 1) {
            __hip_bfloat16 h, l;
            splitf(r, h, l);
            ohi[idx] = h; olo[idx] = l;
        } else {
            out[idx] = r;
            if constexpr (OMODE == 2) out2[idx] = r * di;
        }
    }
}

// G2: t64 = dis ⊙ (H @ W2)
__global__ __launch_bounds__(256) void k_g2(const __hip_bfloat16* __restrict__ Hhi,
                                            const __hip_bfloat16* __restrict__ Hlo,
                                            const __hip_bfloat16* __restrict__ Whi,
                                            const __hip_bfloat16* __restrict__ Wlo,
                                            const int* __restrict__ cursor,
                                            float* __restrict__ t64, int M) {
    __shared__ float smem[128 * 68];
    dev_gemm<0, false, false, true, false, false>(smem, 0, blockIdx.x,
        Hhi, Hlo, nullptr, Whi + W2T_OFF, Wlo + W2T_OFF, nullptr, cursor,
        t64, nullptr, nullptr, M, 128, 64);
}

// G3 (t128 = dis ⊙ relu(AZ@Wa1+ba1)) + G4 (S = relu(AZ@Ws+bs) -> split)
__global__ __launch_bounds__(256) void k_g34(const __hip_bfloat16* __restrict__ AZhi,
                                             const __hip_bfloat16* __restrict__ AZlo,
                                             const __hip_bfloat16* __restrict__ Whi,
                                             const __hip_bfloat16* __restrict__ Wlo,
                                             const float* __restrict__ ba1, const float* __restrict__ bs,
                                             const int* __restrict__ cursor,
                                             float* __restrict__ t128,
                                             __hip_bfloat16* __restrict__ Shi, __hip_bfloat16* __restrict__ Slo,
                                             int M, int Mpad) {
    __shared__ float smem[128 * 68];
    int nt2 = (Mpad / 128) * 2;
    int t = blockIdx.x;
    if (t < nt2)
        dev_gemm<0, true, true, true, false, false>(smem, t & 1, t >> 1,
            AZhi, AZlo, nullptr, Whi + Wa1T_OFF, Wlo + Wa1T_OFF, ba1, cursor,
            t128, nullptr, nullptr, M, 64, 128);
    else
        dev_gemm<0, true, true, false, true, false>(smem, 0, t - nt2,
            AZhi, AZlo, nullptr, Whi + WsT_OFF, Wlo + WsT_OFF, bs, nullptr,
            nullptr, Shi, Slo, M, 64, 64);
}

// tail: G5 (attr, NT) + sst upper-triangle
__global__ __launch_bounds__(256) void k_tail(const __hip_bfloat16* __restrict__ AAhi,
                                              const __hip_bfloat16* __restrict__ AAlo,
                                              const __hip_bfloat16* __restrict__ Whi,
                                              const __hip_bfloat16* __restrict__ Wlo,
                                              const float* __restrict__ ba2,
                                              const __hip_bfloat16* __restrict__ Shi,
                                              const __hip_bfloat16* __restrict__ Slo,
                                              float* __restrict__ attr, float* __restrict__ st,
                                              int M, int Mpad) {
    __shared__ float smem[128 * 68];
    int nt = Mpad / 128;
    int nG5 = 16 * nt;
    int t = blockIdx.x;
    if (t < nG5) {
        dev_gemm<0, true, true, false, false, true>(smem, t & 15, t >> 4,
            AAhi, AAlo, nullptr, Whi + Wa2T_OFF, Wlo + Wa2T_OFF, ba2, nullptr,
            attr, nullptr, nullptr, M, 128, 1024);
    } else {
        int tt = t - nG5;
        int bi = 0;
        while (tt >= nt - bi) { tt -= nt - bi; bi++; }
        dev_sst(smem, bi, bi + tt, Shi, Slo, st, M);
    }
}

// ---------- launch ----------

extern "C" void kernel_launch(void* const* d_in, const int* in_sizes, int n_in,
                              void* d_out, int out_size, void* d_ws, size_t ws_size,
                              hipStream_t stream) {
    const float* x   = (const float*)d_in[0];
    const int*   ei  = (const int*)d_in[1];
    const float* W1  = (const float*)d_in[2];
    const float* b1  = (const float*)d_in[3];
    const float* W2  = (const float*)d_in[4];
    const float* b2  = (const float*)d_in[5];
    const float* Wa1 = (const float*)d_in[6];
    const float* ba1 = (const float*)d_in[7];
    const float* Wa2 = (const float*)d_in[8];
    const float* ba2 = (const float*)d_in[9];
    const float* Ws  = (const float*)d_in[10];
    const float* bs  = (const float*)d_in[11];

    int N = in_sizes[0] / IN_DIM;
    int E = in_sizes[1] / 2;
    int Mpad = ((N + 127) / 128) * 128;
    int nt = Mpad / 128;

    float* out  = (float*)d_out;
    float* attr = out;
    float* st   = out + (size_t)N * IN_DIM;
    float* zout = st + (size_t)N * N;

    char* basep = (char*)d_ws;
    size_t off = 0;
    auto alloc = [&](size_t bytes) -> void* {
        void* p = basep + off;
        off = (off + bytes + 255) & ~(size_t)255;
        return p;
    };
    int*   colPad = (int*)alloc((size_t)N * DEGPAD * 4);
    int*   cursor = (int*)alloc((size_t)N * 4);
    __hip_bfloat16* Whi = (__hip_bfloat16*)alloc((size_t)WT_TOTAL * 2);
    __hip_bfloat16* Wlo = (__hip_bfloat16*)alloc((size_t)WT_TOTAL * 2);
    float* t128 = (float*)alloc((size_t)N * 128 * 4);
    float* t64  = (float*)alloc((size_t)N * 64 * 4);
    float* zp   = (float*)alloc((size_t)N * 64 * 4);
    __hip_bfloat16* Hhi  = (__hip_bfloat16*)alloc((size_t)Mpad * 128 * 2);
    __hip_bfloat16* Hlo  = (__hip_bfloat16*)alloc((size_t)Mpad * 128 * 2);
    __hip_bfloat16* AZhi = (__hip_bfloat16*)alloc((size_t)Mpad * 64 * 2);
    __hip_bfloat16* AZlo = (__hip_bfloat16*)alloc((size_t)Mpad * 64 * 2);
    __hip_bfloat16* AAhi = (__hip_bfloat16*)alloc((size_t)Mpad * 128 * 2);
    __hip_bfloat16* AAlo = (__hip_bfloat16*)alloc((size_t)Mpad * 128 * 2);
    __hip_bfloat16* Shi  = (__hip_bfloat16*)alloc((size_t)Mpad * 64 * 2);
    __hip_bfloat16* Slo  = (__hip_bfloat16*)alloc((size_t)Mpad * 64 * 2);

    dim3 b256(256);
    int spmm_grid = (N * 64 + 255) / 256;

    // 1. prep (cursor zero + weight split)
    k_prep<<<dim3(1104), b256, 0, stream>>>(W1, W2, Wa1, Wa2, Ws, Whi, Wlo, cursor, N);
    // 2. build (edge fill + G1 unscaled)
    k_build<<<dim3(1280), b256, 0, stream>>>(ei, cursor, colPad, E, x, Whi, Wlo, t128, N, Mpad);
    // 3. spmm1 (gather-dis): H = relu(norm-prop(t128) + b1) -> split
    k_spmm<128, true, true, 1, true><<<dim3(spmm_grid), b256, 0, stream>>>(
        t128, colPad, cursor, b1, nullptr, nullptr, Hhi, Hlo, N);
    // 4. G2: t64 = dis ⊙ (H @ W2)
    k_g2<<<dim3(nt), b256, 0, stream>>>(Hhi, Hlo, Whi, Wlo, cursor, t64, N);
    // 5. spmm2 (prescaled): z -> zout (fp32) and zp = dis ⊙ z
    k_spmm<64, true, true, 2, false><<<dim3(spmm_grid), b256, 0, stream>>>(
        t64, colPad, cursor, b2, zout, zp, nullptr, nullptr, N);
    // 6. spmm3 (prescaled): AZ = prop(zp) -> split
    k_spmm<64, false, false, 1, false><<<dim3(spmm_grid), b256, 0, stream>>>(
        zp, colPad, cursor, nullptr, nullptr, nullptr, AZhi, AZlo, N);
    // 7. G3 + G4
    k_g34<<<dim3(3 * nt), b256, 0, stream>>>(AZhi, AZlo, Whi, Wlo, ba1, bs, cursor, t128, Shi, Slo, N, Mpad);
    // 8. spmm4 (prescaled): AA = prop(t128) -> split
    k_spmm<128, false, false, 1, false><<<dim3(spmm_grid), b256, 0, stream>>>(
        t128, colPad, cursor, nullptr, nullptr, nullptr, AAhi, AAlo, N);
    // 9. tail: G5 (attr) + sst upper-triangle (struct)
    k_tail<<<dim3(16 * nt + nt * (nt + 1) / 2), b256, 0, stream>>>(
        AAhi, AAlo, Whi, Wlo, ba2, Shi, Slo, attr, st, N, Mpad);
}

// Round 9
// 300.005 us; speedup vs baseline: 3.3680x; 1.2172x over previous
//
#include <hip/hip_runtime.h>
#include <hip/hip_bf16.h>

#define IN_DIM 1024
#define HID 128
#define LAT 64
#define DEGPAD 128

typedef __attribute__((ext_vector_type(8))) short bf16x8;
typedef __attribute__((ext_vector_type(4))) short bf16x4;
typedef __attribute__((ext_vector_type(4))) float f32x4;

// weight-transpose-split arena offsets (bf16 elements)
#define W1T_OFF 0
#define W2T_OFF 131072
#define Wa1T_OFF 139264
#define Wa2T_OFF 147456
#define WsT_OFF 278528
#define WT_TOTAL 282624

__device__ __forceinline__ void splitf(float v, __hip_bfloat16& h, __hip_bfloat16& l) {
    h = __float2bfloat16(v);
    l = __float2bfloat16(v - __bfloat162float(h));
}

// ---------- dense GEMM tile (block tile 128x64, 4 waves 2x2, wave tile 64x32) ----------
// AMODE 0: A as hi/lo bf16 (rows < Mpad valid memory); AMODE 1: A fp32 row-guarded, in-reg split.
// Epilogue: +bias, relu, then *rsqrt(cursor[row]+1) if DIS (pre-scale for next SpMM).

template<int AMODE, bool BIAS, bool RELU, bool DIS, bool SPLITOUT, bool NT>
__device__ void dev_gemm(float* smem, int bx, int byy,
        const __hip_bfloat16* __restrict__ Ahi, const __hip_bfloat16* __restrict__ Alo,
        const float* __restrict__ Af,
        const __hip_bfloat16* __restrict__ Bthi, const __hip_bfloat16* __restrict__ Btlo,
        const float* __restrict__ bias, const int* __restrict__ cursor,
        float* __restrict__ Cf, __hip_bfloat16* __restrict__ Chi, __hip_bfloat16* __restrict__ Clo,
        int M, int K, int ldc) {
    int tid = threadIdx.x;
    int w = tid >> 6, lane = tid & 63;
    int wr = w >> 1, wc = w & 1;
    int m0 = byy * 128, n0 = bx * 64;
    int lrow = lane & 15, lk = (lane >> 4) * 8;

    int arow[4];
    size_t aoff[4];
#pragma unroll
    for (int mi = 0; mi < 4; ++mi) {
        arow[mi] = m0 + wr * 64 + mi * 16 + lrow;
        aoff[mi] = (size_t)arow[mi] * K + lk;
    }
    size_t boff[2];
#pragma unroll
    for (int nj = 0; nj < 2; ++nj)
        boff[nj] = (size_t)(n0 + wc * 32 + nj * 16 + lrow) * K + lk;

    f32x4 acc[4][2] = {};

    for (int k0 = 0; k0 < K; k0 += 32) {
        bf16x8 bh[2], bl[2], ah[4], al[4];
#pragma unroll
        for (int nj = 0; nj < 2; ++nj) {
            bh[nj] = *(const bf16x8*)(Bthi + boff[nj] + k0);
            bl[nj] = *(const bf16x8*)(Btlo + boff[nj] + k0);
        }
        if constexpr (AMODE == 0) {
#pragma unroll
            for (int mi = 0; mi < 4; ++mi) {
                ah[mi] = *(const bf16x8*)(Ahi + aoff[mi] + k0);
                al[mi] = *(const bf16x8*)(Alo + aoff[mi] + k0);
            }
        } else {
#pragma unroll
            for (int mi = 0; mi < 4; ++mi) {
                float4 f0 = make_float4(0.f, 0.f, 0.f, 0.f), f1 = f0;
                if (arow[mi] < M) {
                    f0 = *(const float4*)(Af + aoff[mi] + k0);
                    f1 = *(const float4*)(Af + aoff[mi] + k0 + 4);
                }
                float ff[8] = {f0.x, f0.y, f0.z, f0.w, f1.x, f1.y, f1.z, f1.w};
                __attribute__((aligned(16))) __hip_bfloat16 hb[8], lb[8];
#pragma unroll
                for (int t = 0; t < 8; ++t) splitf(ff[t], hb[t], lb[t]);
                ah[mi] = *(const bf16x8*)hb;
                al[mi] = *(const bf16x8*)lb;
            }
        }
#pragma unroll
        for (int mi = 0; mi < 4; ++mi)
#pragma unroll
            for (int nj = 0; nj < 2; ++nj) {
                acc[mi][nj] = __builtin_amdgcn_mfma_f32_16x16x32_bf16(ah[mi], bh[nj], acc[mi][nj], 0, 0, 0);
                acc[mi][nj] = __builtin_amdgcn_mfma_f32_16x16x32_bf16(ah[mi], bl[nj], acc[mi][nj], 0, 0, 0);
                acc[mi][nj] = __builtin_amdgcn_mfma_f32_16x16x32_bf16(al[mi], bh[nj], acc[mi][nj], 0, 0, 0);
            }
    }

    // stage to LDS, stride 68 (2-way banks on stage and read — free)
    int r0 = (lane >> 4) * 4;
#pragma unroll
    for (int mi = 0; mi < 4; ++mi)
#pragma unroll
        for (int nj = 0; nj < 2; ++nj) {
            int cl = wc * 32 + nj * 16 + lrow;
#pragma unroll
            for (int r = 0; r < 4; ++r) {
                int rl = wr * 64 + mi * 16 + r0 + r;
                smem[rl * 68 + cl] = acc[mi][nj][r];
            }
        }
    __syncthreads();

#pragma unroll
    for (int it = 0; it < 8; ++it) {
        int rl = it * 16 + (tid >> 4);
        int c4 = tid & 15;
        int row = m0 + rl;
        if (row < M) {
            int col = n0 + c4 * 4;
            float4 v = *(const float4*)&smem[rl * 68 + c4 * 4];
            if (BIAS) {
                float4 b = *(const float4*)&bias[col];
                v.x += b.x; v.y += b.y; v.z += b.z; v.w += b.w;
            }
            if (RELU) {
                v.x = fmaxf(v.x, 0.f); v.y = fmaxf(v.y, 0.f);
                v.z = fmaxf(v.z, 0.f); v.w = fmaxf(v.w, 0.f);
            }
            if (DIS) {
                float di = rsqrtf((float)(cursor[row] + 1));
                v.x *= di; v.y *= di; v.z *= di; v.w *= di;
            }
            if constexpr (SPLITOUT) {
                float vv[4] = {v.x, v.y, v.z, v.w};
                __attribute__((aligned(8))) __hip_bfloat16 hs[4], ls[4];
#pragma unroll
                for (int k = 0; k < 4; ++k) splitf(vv[k], hs[k], ls[k]);
                *(bf16x4*)&Chi[(size_t)row * ldc + col] = *(bf16x4*)hs;
                *(bf16x4*)&Clo[(size_t)row * ldc + col] = *(bf16x4*)ls;
            } else if constexpr (NT) {
                __builtin_nontemporal_store(*(const f32x4*)&v, (f32x4*)&Cf[(size_t)row * ldc + col]);
            } else {
                *(float4*)&Cf[(size_t)row * ldc + col] = v;
            }
        }
    }
    __syncthreads();
}

// ---------- sst 128x128 tile, upper triangle; mirror written DIRECT from acc (float4, full lines) ----------

__device__ void dev_sst(float* smem, int bi, int bj,
                        const __hip_bfloat16* __restrict__ Shi, const __hip_bfloat16* __restrict__ Slo,
                        float* __restrict__ C, int M) {
    int tid = threadIdx.x;
    int w = tid >> 6, lane = tid & 63;
    int wr = w >> 1, wc = w & 1;
    int i0 = bi * 128 + wr * 64;
    int j0 = bj * 128 + wc * 64;
    int lrow = lane & 15, lk = (lane >> 4) * 8;

    f32x4 acc[4][4] = {};
#pragma unroll
    for (int ks = 0; ks < 2; ++ks) {
        bf16x8 ah[4], al[4], bh[4], bl[4];
#pragma unroll
        for (int mi = 0; mi < 4; ++mi) {
            size_t off = (size_t)(i0 + mi * 16 + lrow) * 64 + ks * 32 + lk;
            ah[mi] = *(const bf16x8*)(Shi + off);
            al[mi] = *(const bf16x8*)(Slo + off);
        }
#pragma unroll
        for (int nj = 0; nj < 4; ++nj) {
            size_t off = (size_t)(j0 + nj * 16 + lrow) * 64 + ks * 32 + lk;
            bh[nj] = *(const bf16x8*)(Shi + off);
            bl[nj] = *(const bf16x8*)(Slo + off);
        }
#pragma unroll
        for (int mi = 0; mi < 4; ++mi)
#pragma unroll
            for (int nj = 0; nj < 4; ++nj) {
                acc[mi][nj] = __builtin_amdgcn_mfma_f32_16x16x32_bf16(ah[mi], bh[nj], acc[mi][nj], 0, 0, 0);
                acc[mi][nj] = __builtin_amdgcn_mfma_f32_16x16x32_bf16(ah[mi], bl[nj], acc[mi][nj], 0, 0, 0);
                acc[mi][nj] = __builtin_amdgcn_mfma_f32_16x16x32_bf16(al[mi], bh[nj], acc[mi][nj], 0, 0, 0);
            }
    }

    int r0 = (lane >> 4) * 4;

    // mirror write (C symmetric): acc[mi][nj] = 4 consecutive rows of one col
    // -> 4 consecutive cols of the mirrored tile -> direct float4, 16 rows x 64B lines per instr
    if (bi != bj) {
#pragma unroll
        for (int mi = 0; mi < 4; ++mi)
#pragma unroll
            for (int nj = 0; nj < 4; ++nj) {
                int orow = j0 + nj * 16 + lrow;       // mirrored out row
                int ocol = i0 + mi * 16 + r0;         // mirrored out col (x4)
                if (orow < M && ocol < M) {
                    f32x4 v = acc[mi][nj];
                    __builtin_nontemporal_store(v, (f32x4*)&C[(size_t)orow * M + ocol]);
                }
            }
    }

    // normal write via LDS transpose, two 64-col passes (34KB)
#pragma unroll
    for (int p = 0; p < 2; ++p) {
        if (wc == p) {
#pragma unroll
            for (int mi = 0; mi < 4; ++mi)
#pragma unroll
                for (int nj = 0; nj < 4; ++nj) {
                    int cl = nj * 16 + lrow;
#pragma unroll
                    for (int r = 0; r < 4; ++r) {
                        int rl = wr * 64 + mi * 16 + r0 + r;
                        smem[rl * 68 + cl] = acc[mi][nj][r];
                    }
                }
        }
        __syncthreads();
#pragma unroll
        for (int it = 0; it < 8; ++it) {
            int rl = it * 16 + (tid >> 4);
            int c4 = tid & 15;
            int row = bi * 128 + rl;
            int col = bj * 128 + p * 64 + c4 * 4;
            if (row < M && col < M) {
                float4 v = *(const float4*)&smem[rl * 68 + c4 * 4];
                __builtin_nontemporal_store(*(const f32x4*)&v, (f32x4*)&C[(size_t)row * M + col]);
            }
        }
        __syncthreads();
    }
}

// ---------- kernels ----------

// prep: cursor = 0, weight transpose+split
__global__ __launch_bounds__(256) void k_prep(const float* __restrict__ W1, const float* __restrict__ W2,
                                              const float* __restrict__ Wa1, const float* __restrict__ Wa2,
                                              const float* __restrict__ Ws,
                                              __hip_bfloat16* __restrict__ hi, __hip_bfloat16* __restrict__ lo,
                                              int* cursor, int N) {
    int gtid = blockIdx.x * 256 + threadIdx.x;
    int gsz = gridDim.x * 256;
    for (int i = gtid; i < N; i += gsz) cursor[i] = 0;
    for (int idx = gtid; idx < WT_TOTAL; idx += gsz) {
        const float* src; int base, shK, Nc;
        if (idx < W2T_OFF)       { src = W1;  base = W1T_OFF;  shK = 10; Nc = 128; }
        else if (idx < Wa1T_OFF) { src = W2;  base = W2T_OFF;  shK = 7;  Nc = 64; }
        else if (idx < Wa2T_OFF) { src = Wa1; base = Wa1T_OFF; shK = 6;  Nc = 128; }
        else if (idx < WsT_OFF)  { src = Wa2; base = Wa2T_OFF; shK = 7;  Nc = 1024; }
        else                     { src = Ws;  base = WsT_OFF;  shK = 6;  Nc = 64; }
        int local = idx - base;
        int nn = local >> shK;
        int k = local & ((1 << shK) - 1);
        splitf(src[(size_t)k * Nc + nn], hi[idx], lo[idx]);
    }
}

// build: edge fill (atomics) + G1 (t128 = x @ W1, unscaled — cursor not final here)
__global__ __launch_bounds__(256) void k_build(const int* __restrict__ ei, int* cursor,
                                               int* __restrict__ colPad, int E,
                                               const float* __restrict__ x,
                                               const __hip_bfloat16* __restrict__ Whi,
                                               const __hip_bfloat16* __restrict__ Wlo,
                                               float* __restrict__ t128, int M, int Mpad) {
    __shared__ float smem[128 * 68];
    int gtid = blockIdx.x * 256 + threadIdx.x;
    int gsz = gridDim.x * 256;
    for (int e = gtid; e < E; e += gsz) {
        int s = ei[e], r = ei[E + e];
        int slot = atomicAdd(&cursor[r], 1);
        if (slot < DEGPAD) colPad[(size_t)r * DEGPAD + slot] = s;
    }
    int nt2 = (Mpad / 128) * 2;
    for (int t = blockIdx.x; t < nt2; t += gridDim.x)
        dev_gemm<1, false, false, false, false, false>(smem, t & 1, t >> 1,
            nullptr, nullptr, x, Whi + W1T_OFF, Wlo + W1T_OFF, nullptr, nullptr,
            t128, nullptr, nullptr, M, 1024, 128);
}

// SpMM, ILP-unrolled gather (int4 index loads, 4 neighbors in flight).
// GD: per-neighbor dc=rsqrt(cursor[c]+1) (input unscaled); else input pre-scaled by producer.
// OMODE 0: fp32; 1: split bf16; 2: fp32 + prescaled copy.
template<int F, bool BIAS, bool RELU, int OMODE, bool GD>
__global__ __launch_bounds__(256) void k_spmm(const float* __restrict__ Hin,
                                              const int* __restrict__ colPad,
                                              const int* __restrict__ cursor,
                                              const float* __restrict__ bias,
                                              float* __restrict__ out, float* __restrict__ out2,
                                              __hip_bfloat16* __restrict__ ohi,
                                              __hip_bfloat16* __restrict__ olo, int n) {
    constexpr int JW = F / 64;
    int i = (blockIdx.x * 256 + threadIdx.x) >> 6;
    int lane = threadIdx.x & 63;
    if (i >= n) return;
    int d = cursor[i];
    float di = rsqrtf((float)(d + 1));
    if (d > DEGPAD) d = DEGPAD;
    const int* cp = colPad + (size_t)i * DEGPAD;
    float acc[JW];
    const float* self = Hin + (size_t)i * F;
#pragma unroll
    for (int j = 0; j < JW; ++j) acc[j] = (GD ? di : 1.f) * self[lane + 64 * j];

    int p = 0;
    for (; p + 4 <= d; p += 4) {
        int4 cidx = *(const int4*)(cp + p);
        int cc[4] = {cidx.x, cidx.y, cidx.z, cidx.w};
        float dc[4];
        if constexpr (GD) {
#pragma unroll
            for (int q = 0; q < 4; ++q) dc[q] = rsqrtf((float)(cursor[cc[q]] + 1));
        }
        float vals[4][JW];
#pragma unroll
        for (int q = 0; q < 4; ++q) {
            const float* row = Hin + (size_t)cc[q] * F;
#pragma unroll
            for (int j = 0; j < JW; ++j) vals[q][j] = row[lane + 64 * j];
        }
#pragma unroll
        for (int q = 0; q < 4; ++q)
#pragma unroll
            for (int j = 0; j < JW; ++j)
                acc[j] = GD ? fmaf(dc[q], vals[q][j], acc[j]) : (acc[j] + vals[q][j]);
    }
    for (; p < d; ++p) {
        int c = cp[p];
        const float* row = Hin + (size_t)c * F;
        if constexpr (GD) {
            float dc = rsqrtf((float)(cursor[c] + 1));
#pragma unroll
            for (int j = 0; j < JW; ++j) acc[j] = fmaf(dc, row[lane + 64 * j], acc[j]);
        } else {
#pragma unroll
            for (int j = 0; j < JW; ++j) acc[j] += row[lane + 64 * j];
        }
    }

#pragma unroll
    for (int j = 0; j < JW; ++j) {
        float r = acc[j] * di;
        if (BIAS) r += bias[lane + 64 * j];
        if (RELU) r = fmaxf(r, 0.f);
        size_t idx = (size_t)i * F + lane + 64 * j;
        if constexpr (OMODE == 1) {
            __hip_bfloat16 h, l;
            splitf(r, h, l);
            ohi[idx] = h; olo[idx] = l;
        } else {
            out[idx] = r;
            if constexpr (OMODE == 2) out2[idx] = r * di;
        }
    }
}

// G2: t64 = dis ⊙ (H @ W2)
__global__ __launch_bounds__(256) void k_g2(const __hip_bfloat16* __restrict__ Hhi,
                                            const __hip_bfloat16* __restrict__ Hlo,
                                            const __hip_bfloat16* __restrict__ Whi,
                                            const __hip_bfloat16* __restrict__ Wlo,
                                            const int* __restrict__ cursor,
                                            float* __restrict__ t64, int M) {
    __shared__ float smem[128 * 68];
    dev_gemm<0, false, false, true, false, false>(smem, 0, blockIdx.x,
        Hhi, Hlo, nullptr, Whi + W2T_OFF, Wlo + W2T_OFF, nullptr, cursor,
        t64, nullptr, nullptr, M, 128, 64);
}

// G3 (t128 = dis ⊙ relu(AZ@Wa1+ba1)) + G4 (S = relu(AZ@Ws+bs) -> split)
__global__ __launch_bounds__(256) void k_g34(const __hip_bfloat16* __restrict__ AZhi,
                                             const __hip_bfloat16* __restrict__ AZlo,
                                             const __hip_bfloat16* __restrict__ Whi,
                                             const __hip_bfloat16* __restrict__ Wlo,
                                             const float* __restrict__ ba1, const float* __restrict__ bs,
                                             const int* __restrict__ cursor,
                                             float* __restrict__ t128,
                                             __hip_bfloat16* __restrict__ Shi, __hip_bfloat16* __restrict__ Slo,
                                             int M, int Mpad) {
    __shared__ float smem[128 * 68];
    int nt2 = (Mpad / 128) * 2;
    int t = blockIdx.x;
    if (t < nt2)
        dev_gemm<0, true, true, true, false, false>(smem, t & 1, t >> 1,
            AZhi, AZlo, nullptr, Whi + Wa1T_OFF, Wlo + Wa1T_OFF, ba1, cursor,
            t128, nullptr, nullptr, M, 64, 128);
    else
        dev_gemm<0, true, true, false, true, false>(smem, 0, t - nt2,
            AZhi, AZlo, nullptr, Whi + WsT_OFF, Wlo + WsT_OFF, bs, nullptr,
            nullptr, Shi, Slo, M, 64, 64);
}

// tail: G5 (attr, NT) + sst upper-triangle
__global__ __launch_bounds__(256) void k_tail(const __hip_bfloat16* __restrict__ AAhi,
                                              const __hip_bfloat16* __restrict__ AAlo,
                                              const __hip_bfloat16* __restrict__ Whi,
                                              const __hip_bfloat16* __restrict__ Wlo,
                                              const float* __restrict__ ba2,
                                              const __hip_bfloat16* __restrict__ Shi,
                                              const __hip_bfloat16* __restrict__ Slo,
                                              float* __restrict__ attr, float* __restrict__ st,
                                              int M, int Mpad) {
    __shared__ float smem[128 * 68];
    int nt = Mpad / 128;
    int nG5 = 16 * nt;
    int t = blockIdx.x;
    if (t < nG5) {
        dev_gemm<0, true, true, false, false, true>(smem, t & 15, t >> 4,
            AAhi, AAlo, nullptr, Whi + Wa2T_OFF, Wlo + Wa2T_OFF, ba2, nullptr,
            attr, nullptr, nullptr, M, 128, 1024);
    } else {
        int tt = t - nG5;
        int bi = 0;
        while (tt >= nt - bi) { tt -= nt - bi; bi++; }
        dev_sst(smem, bi, bi + tt, Shi, Slo, st, M);
    }
}

// ---------- launch ----------

extern "C" void kernel_launch(void* const* d_in, const int* in_sizes, int n_in,
                              void* d_out, int out_size, void* d_ws, size_t ws_size,
                              hipStream_t stream) {
    const float* x   = (const float*)d_in[0];
    const int*   ei  = (const int*)d_in[1];
    const float* W1  = (const float*)d_in[2];
    const float* b1  = (const float*)d_in[3];
    const float* W2  = (const float*)d_in[4];
    const float* b2  = (const float*)d_in[5];
    const float* Wa1 = (const float*)d_in[6];
    const float* ba1 = (const float*)d_in[7];
    const float* Wa2 = (const float*)d_in[8];
    const float* ba2 = (const float*)d_in[9];
    const float* Ws  = (const float*)d_in[10];
    const float* bs  = (const float*)d_in[11];

    int N = in_sizes[0] / IN_DIM;
    int E = in_sizes[1] / 2;
    int Mpad = ((N + 127) / 128) * 128;
    int nt = Mpad / 128;

    float* out  = (float*)d_out;
    float* attr = out;
    float* st   = out + (size_t)N * IN_DIM;
    float* zout = st + (size_t)N * N;

    char* basep = (char*)d_ws;
    size_t off = 0;
    auto alloc = [&](size_t bytes) -> void* {
        void* p = basep + off;
        off = (off + bytes + 255) & ~(size_t)255;
        return p;
    };
    int*   colPad = (int*)alloc((size_t)N * DEGPAD * 4);
    int*   cursor = (int*)alloc((size_t)N * 4);
    __hip_bfloat16* Whi = (__hip_bfloat16*)alloc((size_t)WT_TOTAL * 2);
    __hip_bfloat16* Wlo = (__hip_bfloat16*)alloc((size_t)WT_TOTAL * 2);
    float* t128 = (float*)alloc((size_t)N * 128 * 4);
    float* t64  = (float*)alloc((size_t)N * 64 * 4);
    float* zp   = (float*)alloc((size_t)N * 64 * 4);
    __hip_bfloat16* Hhi  = (__hip_bfloat16*)alloc((size_t)Mpad * 128 * 2);
    __hip_bfloat16* Hlo  = (__hip_bfloat16*)alloc((size_t)Mpad * 128 * 2);
    __hip_bfloat16* AZhi = (__hip_bfloat16*)alloc((size_t)Mpad * 64 * 2);
    __hip_bfloat16* AZlo = (__hip_bfloat16*)alloc((size_t)Mpad * 64 * 2);
    __hip_bfloat16* AAhi = (__hip_bfloat16*)alloc((size_t)Mpad * 128 * 2);
    __hip_bfloat16* AAlo = (__hip_bfloat16*)alloc((size_t)Mpad * 128 * 2);
    __hip_bfloat16* Shi  = (__hip_bfloat16*)alloc((size_t)Mpad * 64 * 2);
    __hip_bfloat16* Slo  = (__hip_bfloat16*)alloc((size_t)Mpad * 64 * 2);

    dim3 b256(256);
    int spmm_grid = (N * 64 + 255) / 256;

    // 1. prep (cursor zero + weight split)
    k_prep<<<dim3(1104), b256, 0, stream>>>(W1, W2, Wa1, Wa2, Ws, Whi, Wlo, cursor, N);
    // 2. build (edge fill + G1 unscaled)
    k_build<<<dim3(1280), b256, 0, stream>>>(ei, cursor, colPad, E, x, Whi, Wlo, t128, N, Mpad);
    // 3. spmm1 (gather-dis): H = relu(norm-prop(t128) + b1) -> split
    k_spmm<128, true, true, 1, true><<<dim3(spmm_grid), b256, 0, stream>>>(
        t128, colPad, cursor, b1, nullptr, nullptr, Hhi, Hlo, N);
    // 4. G2: t64 = dis ⊙ (H @ W2)
    k_g2<<<dim3(nt), b256, 0, stream>>>(Hhi, Hlo, Whi, Wlo, cursor, t64, N);
    // 5. spmm2 (prescaled): z -> zout (fp32) and zp = dis ⊙ z
    k_spmm<64, true, true, 2, false><<<dim3(spmm_grid), b256, 0, stream>>>(
        t64, colPad, cursor, b2, zout, zp, nullptr, nullptr, N);
    // 6. spmm3 (prescaled): AZ = prop(zp) -> split
    k_spmm<64, false, false, 1, false><<<dim3(spmm_grid), b256, 0, stream>>>(
        zp, colPad, cursor, nullptr, nullptr, nullptr, AZhi, AZlo, N);
    // 7. G3 + G4
    k_g34<<<dim3(3 * nt), b256, 0, stream>>>(AZhi, AZlo, Whi, Wlo, ba1, bs, cursor, t128, Shi, Slo, N, Mpad);
    // 8. spmm4 (prescaled): AA = prop(t128) -> split
    k_spmm<128, false, false, 1, false><<<dim3(spmm_grid), b256, 0, stream>>>(
        t128, colPad, cursor, nullptr, nullptr, nullptr, AAhi, AAlo, N);
    // 9. tail: G5 (attr) + sst upper-triangle (struct)
    k_tail<<<dim3(16 * nt + nt * (nt + 1) / 2), b256, 0, stream>>>(
        AAhi, AAlo, Whi, Wlo, ba2, Shi, Slo, attr, st, N, Mpad);
}

// Round 10
// 299.349 us; speedup vs baseline: 3.3754x; 1.0022x over previous
//
#include <hip/hip_runtime.h>
#include <hip/hip_bf16.h>

#define IN_DIM 1024
#define HID 128
#define LAT 64
#define DEGPAD 128

typedef __attribute__((ext_vector_type(8))) short bf16x8;
typedef __attribute__((ext_vector_type(4))) short bf16x4;
typedef __attribute__((ext_vector_type(4))) float f32x4;

// weight-transpose-split arena offsets (bf16 elements)
#define W1T_OFF 0
#define W2T_OFF 131072
#define Wa1T_OFF 139264
#define Wa2T_OFF 147456
#define WsT_OFF 278528
#define WT_TOTAL 282624

__device__ __forceinline__ void splitf(float v, __hip_bfloat16& h, __hip_bfloat16& l) {
    h = __float2bfloat16(v);
    l = __float2bfloat16(v - __bfloat162float(h));
}

// ---------- dense GEMM tile (block tile 128x64, 4 waves 2x2, wave tile 64x32) ----------
// AMODE 0: A as hi/lo bf16 (rows < Mpad valid memory); AMODE 1: A fp32 row-guarded, in-reg split.
// Epilogue: +bias, relu, then *rsqrt(cursor[row]+1) if DIS (pre-scale for next SpMM).

template<int AMODE, bool BIAS, bool RELU, bool DIS, bool SPLITOUT, bool NT>
__device__ void dev_gemm(float* smem, int bx, int byy,
        const __hip_bfloat16* __restrict__ Ahi, const __hip_bfloat16* __restrict__ Alo,
        const float* __restrict__ Af,
        const __hip_bfloat16* __restrict__ Bthi, const __hip_bfloat16* __restrict__ Btlo,
        const float* __restrict__ bias, const int* __restrict__ cursor,
        float* __restrict__ Cf, __hip_bfloat16* __restrict__ Chi, __hip_bfloat16* __restrict__ Clo,
        int M, int K, int ldc) {
    int tid = threadIdx.x;
    int w = tid >> 6, lane = tid & 63;
    int wr = w >> 1, wc = w & 1;
    int m0 = byy * 128, n0 = bx * 64;
    int lrow = lane & 15, lk = (lane >> 4) * 8;

    int arow[4];
    size_t aoff[4];
#pragma unroll
    for (int mi = 0; mi < 4; ++mi) {
        arow[mi] = m0 + wr * 64 + mi * 16 + lrow;
        aoff[mi] = (size_t)arow[mi] * K + lk;
    }
    size_t boff[2];
#pragma unroll
    for (int nj = 0; nj < 2; ++nj)
        boff[nj] = (size_t)(n0 + wc * 32 + nj * 16 + lrow) * K + lk;

    f32x4 acc[4][2] = {};

    for (int k0 = 0; k0 < K; k0 += 32) {
        bf16x8 bh[2], bl[2], ah[4], al[4];
#pragma unroll
        for (int nj = 0; nj < 2; ++nj) {
            bh[nj] = *(const bf16x8*)(Bthi + boff[nj] + k0);
            bl[nj] = *(const bf16x8*)(Btlo + boff[nj] + k0);
        }
        if constexpr (AMODE == 0) {
#pragma unroll
            for (int mi = 0; mi < 4; ++mi) {
                ah[mi] = *(const bf16x8*)(Ahi + aoff[mi] + k0);
                al[mi] = *(const bf16x8*)(Alo + aoff[mi] + k0);
            }
        } else {
#pragma unroll
            for (int mi = 0; mi < 4; ++mi) {
                float4 f0 = make_float4(0.f, 0.f, 0.f, 0.f), f1 = f0;
                if (arow[mi] < M) {
                    f0 = *(const float4*)(Af + aoff[mi] + k0);
                    f1 = *(const float4*)(Af + aoff[mi] + k0 + 4);
                }
                float ff[8] = {f0.x, f0.y, f0.z, f0.w, f1.x, f1.y, f1.z, f1.w};
                __attribute__((aligned(16))) __hip_bfloat16 hb[8], lb[8];
#pragma unroll
                for (int t = 0; t < 8; ++t) splitf(ff[t], hb[t], lb[t]);
                ah[mi] = *(const bf16x8*)hb;
                al[mi] = *(const bf16x8*)lb;
            }
        }
#pragma unroll
        for (int mi = 0; mi < 4; ++mi)
#pragma unroll
            for (int nj = 0; nj < 2; ++nj) {
                acc[mi][nj] = __builtin_amdgcn_mfma_f32_16x16x32_bf16(ah[mi], bh[nj], acc[mi][nj], 0, 0, 0);
                acc[mi][nj] = __builtin_amdgcn_mfma_f32_16x16x32_bf16(ah[mi], bl[nj], acc[mi][nj], 0, 0, 0);
                acc[mi][nj] = __builtin_amdgcn_mfma_f32_16x16x32_bf16(al[mi], bh[nj], acc[mi][nj], 0, 0, 0);
            }
    }

    // stage to LDS, stride 68 (2-way banks on stage and read — free)
    int r0 = (lane >> 4) * 4;
#pragma unroll
    for (int mi = 0; mi < 4; ++mi)
#pragma unroll
        for (int nj = 0; nj < 2; ++nj) {
            int cl = wc * 32 + nj * 16 + lrow;
#pragma unroll
            for (int r = 0; r < 4; ++r) {
                int rl = wr * 64 + mi * 16 + r0 + r;
                smem[rl * 68 + cl] = acc[mi][nj][r];
            }
        }
    __syncthreads();

#pragma unroll
    for (int it = 0; it < 8; ++it) {
        int rl = it * 16 + (tid >> 4);
        int c4 = tid & 15;
        int row = m0 + rl;
        if (row < M) {
            int col = n0 + c4 * 4;
            float4 v = *(const float4*)&smem[rl * 68 + c4 * 4];
            if (BIAS) {
                float4 b = *(const float4*)&bias[col];
                v.x += b.x; v.y += b.y; v.z += b.z; v.w += b.w;
            }
            if (RELU) {
                v.x = fmaxf(v.x, 0.f); v.y = fmaxf(v.y, 0.f);
                v.z = fmaxf(v.z, 0.f); v.w = fmaxf(v.w, 0.f);
            }
            if (DIS) {
                float di = rsqrtf((float)(cursor[row] + 1));
                v.x *= di; v.y *= di; v.z *= di; v.w *= di;
            }
            if constexpr (SPLITOUT) {
                float vv[4] = {v.x, v.y, v.z, v.w};
                __attribute__((aligned(8))) __hip_bfloat16 hs[4], ls[4];
#pragma unroll
                for (int k = 0; k < 4; ++k) splitf(vv[k], hs[k], ls[k]);
                *(bf16x4*)&Chi[(size_t)row * ldc + col] = *(bf16x4*)hs;
                *(bf16x4*)&Clo[(size_t)row * ldc + col] = *(bf16x4*)ls;
            } else if constexpr (NT) {
                __builtin_nontemporal_store(*(const f32x4*)&v, (f32x4*)&Cf[(size_t)row * ldc + col]);
            } else {
                *(float4*)&Cf[(size_t)row * ldc + col] = v;
            }
        }
    }
    __syncthreads();
}

// ---------- sst 128x128 tile, upper triangle; mirror written DIRECT from acc (float4, full lines) ----------

__device__ void dev_sst(float* smem, int bi, int bj,
                        const __hip_bfloat16* __restrict__ Shi, const __hip_bfloat16* __restrict__ Slo,
                        float* __restrict__ C, int M) {
    int tid = threadIdx.x;
    int w = tid >> 6, lane = tid & 63;
    int wr = w >> 1, wc = w & 1;
    int i0 = bi * 128 + wr * 64;
    int j0 = bj * 128 + wc * 64;
    int lrow = lane & 15, lk = (lane >> 4) * 8;

    f32x4 acc[4][4] = {};
#pragma unroll
    for (int ks = 0; ks < 2; ++ks) {
        bf16x8 ah[4], al[4], bh[4], bl[4];
#pragma unroll
        for (int mi = 0; mi < 4; ++mi) {
            size_t off = (size_t)(i0 + mi * 16 + lrow) * 64 + ks * 32 + lk;
            ah[mi] = *(const bf16x8*)(Shi + off);
            al[mi] = *(const bf16x8*)(Slo + off);
        }
#pragma unroll
        for (int nj = 0; nj < 4; ++nj) {
            size_t off = (size_t)(j0 + nj * 16 + lrow) * 64 + ks * 32 + lk;
            bh[nj] = *(const bf16x8*)(Shi + off);
            bl[nj] = *(const bf16x8*)(Slo + off);
        }
#pragma unroll
        for (int mi = 0; mi < 4; ++mi)
#pragma unroll
            for (int nj = 0; nj < 4; ++nj) {
                acc[mi][nj] = __builtin_amdgcn_mfma_f32_16x16x32_bf16(ah[mi], bh[nj], acc[mi][nj], 0, 0, 0);
                acc[mi][nj] = __builtin_amdgcn_mfma_f32_16x16x32_bf16(ah[mi], bl[nj], acc[mi][nj], 0, 0, 0);
                acc[mi][nj] = __builtin_amdgcn_mfma_f32_16x16x32_bf16(al[mi], bh[nj], acc[mi][nj], 0, 0, 0);
            }
    }

    int r0 = (lane >> 4) * 4;

    // mirror write (C symmetric): acc[mi][nj] = 4 consecutive rows of one col
    // -> 4 consecutive cols of the mirrored tile -> direct float4, 16 rows x 64B lines per instr
    if (bi != bj) {
#pragma unroll
        for (int mi = 0; mi < 4; ++mi)
#pragma unroll
            for (int nj = 0; nj < 4; ++nj) {
                int orow = j0 + nj * 16 + lrow;       // mirrored out row
                int ocol = i0 + mi * 16 + r0;         // mirrored out col (x4)
                if (orow < M && ocol < M) {
                    f32x4 v = acc[mi][nj];
                    __builtin_nontemporal_store(v, (f32x4*)&C[(size_t)orow * M + ocol]);
                }
            }
    }

    // normal write via LDS transpose, two 64-col passes (34KB)
#pragma unroll
    for (int p = 0; p < 2; ++p) {
        if (wc == p) {
#pragma unroll
            for (int mi = 0; mi < 4; ++mi)
#pragma unroll
                for (int nj = 0; nj < 4; ++nj) {
                    int cl = nj * 16 + lrow;
#pragma unroll
                    for (int r = 0; r < 4; ++r) {
                        int rl = wr * 64 + mi * 16 + r0 + r;
                        smem[rl * 68 + cl] = acc[mi][nj][r];
                    }
                }
        }
        __syncthreads();
#pragma unroll
        for (int it = 0; it < 8; ++it) {
            int rl = it * 16 + (tid >> 4);
            int c4 = tid & 15;
            int row = bi * 128 + rl;
            int col = bj * 128 + p * 64 + c4 * 4;
            if (row < M && col < M) {
                float4 v = *(const float4*)&smem[rl * 68 + c4 * 4];
                __builtin_nontemporal_store(*(const f32x4*)&v, (f32x4*)&C[(size_t)row * M + col]);
            }
        }
        __syncthreads();
    }
}

// ---------- kernels ----------

// prep: weight transpose+split + edge fill (cursor pre-zeroed by memset)
__global__ __launch_bounds__(256) void k_prep(const float* __restrict__ W1, const float* __restrict__ W2,
                                              const float* __restrict__ Wa1, const float* __restrict__ Wa2,
                                              const float* __restrict__ Ws,
                                              __hip_bfloat16* __restrict__ hi, __hip_bfloat16* __restrict__ lo,
                                              const int* __restrict__ ei, int* cursor,
                                              int* __restrict__ colPad, int E) {
    int gtid = blockIdx.x * 256 + threadIdx.x;
    int gsz = gridDim.x * 256;
    for (int e = gtid; e < E; e += gsz) {
        int s = ei[e], r = ei[E + e];
        int slot = atomicAdd(&cursor[r], 1);
        if (slot < DEGPAD) colPad[(size_t)r * DEGPAD + slot] = s;
    }
    for (int idx = gtid; idx < WT_TOTAL; idx += gsz) {
        const float* src; int base, shK, Nc;
        if (idx < W2T_OFF)       { src = W1;  base = W1T_OFF;  shK = 10; Nc = 128; }
        else if (idx < Wa1T_OFF) { src = W2;  base = W2T_OFF;  shK = 7;  Nc = 64; }
        else if (idx < Wa2T_OFF) { src = Wa1; base = Wa1T_OFF; shK = 6;  Nc = 128; }
        else if (idx < WsT_OFF)  { src = Wa2; base = Wa2T_OFF; shK = 7;  Nc = 1024; }
        else                     { src = Ws;  base = WsT_OFF;  shK = 6;  Nc = 64; }
        int local = idx - base;
        int nn = local >> shK;
        int k = local & ((1 << shK) - 1);
        splitf(src[(size_t)k * Nc + nn], hi[idx], lo[idx]);
    }
}

// G1: t128 = dis ⊙ (x @ W1)  (fp32 A, in-reg split; cursor final -> DIS epilogue)
__global__ __launch_bounds__(256) void k_g1(const float* __restrict__ x,
                                            const __hip_bfloat16* __restrict__ Whi,
                                            const __hip_bfloat16* __restrict__ Wlo,
                                            const int* __restrict__ cursor,
                                            float* __restrict__ t128, int M) {
    __shared__ float smem[128 * 68];
    int t = blockIdx.x;
    dev_gemm<1, false, false, true, false, false>(smem, t & 1, t >> 1,
        nullptr, nullptr, x, Whi + W1T_OFF, Wlo + W1T_OFF, nullptr, cursor,
        t128, nullptr, nullptr, M, 1024, 128);
}

// SpMM, 8-deep ILP gather (input pre-scaled by producer).
// OMODE 0: fp32; 1: split bf16; 2: fp32 + prescaled copy.
template<int F, bool BIAS, bool RELU, int OMODE>
__global__ __launch_bounds__(256) void k_spmm(const float* __restrict__ Hin,
                                              const int* __restrict__ colPad,
                                              const int* __restrict__ cursor,
                                              const float* __restrict__ bias,
                                              float* __restrict__ out, float* __restrict__ out2,
                                              __hip_bfloat16* __restrict__ ohi,
                                              __hip_bfloat16* __restrict__ olo, int n) {
    constexpr int JW = F / 64;
    int i = (blockIdx.x * 256 + threadIdx.x) >> 6;
    int lane = threadIdx.x & 63;
    if (i >= n) return;
    int d = cursor[i];
    float di = rsqrtf((float)(d + 1));
    if (d > DEGPAD) d = DEGPAD;
    const int* cp = colPad + (size_t)i * DEGPAD;
    float acc[JW];
    const float* self = Hin + (size_t)i * F;
#pragma unroll
    for (int j = 0; j < JW; ++j) acc[j] = self[lane + 64 * j];

    int p = 0;
    for (; p + 8 <= d; p += 8) {
        int4 ca = *(const int4*)(cp + p);
        int4 cb = *(const int4*)(cp + p + 4);
        int cc[8] = {ca.x, ca.y, ca.z, ca.w, cb.x, cb.y, cb.z, cb.w};
        float vals[8][JW];
#pragma unroll
        for (int q = 0; q < 8; ++q) {
            const float* row = Hin + (size_t)cc[q] * F;
#pragma unroll
            for (int j = 0; j < JW; ++j) vals[q][j] = row[lane + 64 * j];
        }
#pragma unroll
        for (int q = 0; q < 8; ++q)
#pragma unroll
            for (int j = 0; j < JW; ++j) acc[j] += vals[q][j];
    }
    for (; p + 4 <= d; p += 4) {
        int4 ca = *(const int4*)(cp + p);
        int cc[4] = {ca.x, ca.y, ca.z, ca.w};
        float vals[4][JW];
#pragma unroll
        for (int q = 0; q < 4; ++q) {
            const float* row = Hin + (size_t)cc[q] * F;
#pragma unroll
            for (int j = 0; j < JW; ++j) vals[q][j] = row[lane + 64 * j];
        }
#pragma unroll
        for (int q = 0; q < 4; ++q)
#pragma unroll
            for (int j = 0; j < JW; ++j) acc[j] += vals[q][j];
    }
    for (; p < d; ++p) {
        const float* row = Hin + (size_t)cp[p] * F;
#pragma unroll
        for (int j = 0; j < JW; ++j) acc[j] += row[lane + 64 * j];
    }

#pragma unroll
    for (int j = 0; j < JW; ++j) {
        float r = acc[j] * di;
        if (BIAS) r += bias[lane + 64 * j];
        if (RELU) r = fmaxf(r, 0.f);
        size_t idx = (size_t)i * F + lane + 64 * j;
        if constexpr (OMODE == 1) {
            __hip_bfloat16 h, l;
            splitf(r, h, l);
            ohi[idx] = h; olo[idx] = l;
        } else {
            out[idx] = r;
            if constexpr (OMODE == 2) out2[idx] = r * di;
        }
    }
}

// G2: t64 = dis ⊙ (H @ W2)
__global__ __launch_bounds__(256) void k_g2(const __hip_bfloat16* __restrict__ Hhi,
                                            const __hip_bfloat16* __restrict__ Hlo,
                                            const __hip_bfloat16* __restrict__ Whi,
                                            const __hip_bfloat16* __restrict__ Wlo,
                                            const int* __restrict__ cursor,
                                            float* __restrict__ t64, int M) {
    __shared__ float smem[128 * 68];
    dev_gemm<0, false, false, true, false, false>(smem, 0, blockIdx.x,
        Hhi, Hlo, nullptr, Whi + W2T_OFF, Wlo + W2T_OFF, nullptr, cursor,
        t64, nullptr, nullptr, M, 128, 64);
}

// G3 (t128 = dis ⊙ relu(AZ@Wa1+ba1)) + G4 (S = relu(AZ@Ws+bs) -> split)
__global__ __launch_bounds__(256) void k_g34(const __hip_bfloat16* __restrict__ AZhi,
                                             const __hip_bfloat16* __restrict__ AZlo,
                                             const __hip_bfloat16* __restrict__ Whi,
                                             const __hip_bfloat16* __restrict__ Wlo,
                                             const float* __restrict__ ba1, const float* __restrict__ bs,
                                             const int* __restrict__ cursor,
                                             float* __restrict__ t128,
                                             __hip_bfloat16* __restrict__ Shi, __hip_bfloat16* __restrict__ Slo,
                                             int M, int Mpad) {
    __shared__ float smem[128 * 68];
    int nt2 = (Mpad / 128) * 2;
    int t = blockIdx.x;
    if (t < nt2)
        dev_gemm<0, true, true, true, false, false>(smem, t & 1, t >> 1,
            AZhi, AZlo, nullptr, Whi + Wa1T_OFF, Wlo + Wa1T_OFF, ba1, cursor,
            t128, nullptr, nullptr, M, 64, 128);
    else
        dev_gemm<0, true, true, false, true, false>(smem, 0, t - nt2,
            AZhi, AZlo, nullptr, Whi + WsT_OFF, Wlo + WsT_OFF, bs, nullptr,
            nullptr, Shi, Slo, M, 64, 64);
}

// tail: G5 (attr, NT) + sst upper-triangle
__global__ __launch_bounds__(256) void k_tail(const __hip_bfloat16* __restrict__ AAhi,
                                              const __hip_bfloat16* __restrict__ AAlo,
                                              const __hip_bfloat16* __restrict__ Whi,
                                              const __hip_bfloat16* __restrict__ Wlo,
                                              const float* __restrict__ ba2,
                                              const __hip_bfloat16* __restrict__ Shi,
                                              const __hip_bfloat16* __restrict__ Slo,
                                              float* __restrict__ attr, float* __restrict__ st,
                                              int M, int Mpad) {
    __shared__ float smem[128 * 68];
    int nt = Mpad / 128;
    int nG5 = 16 * nt;
    int t = blockIdx.x;
    if (t < nG5) {
        dev_gemm<0, true, true, false, false, true>(smem, t & 15, t >> 4,
            AAhi, AAlo, nullptr, Whi + Wa2T_OFF, Wlo + Wa2T_OFF, ba2, nullptr,
            attr, nullptr, nullptr, M, 128, 1024);
    } else {
        int tt = t - nG5;
        int bi = 0;
        while (tt >= nt - bi) { tt -= nt - bi; bi++; }
        dev_sst(smem, bi, bi + tt, Shi, Slo, st, M);
    }
}

// ---------- launch ----------

extern "C" void kernel_launch(void* const* d_in, const int* in_sizes, int n_in,
                              void* d_out, int out_size, void* d_ws, size_t ws_size,
                              hipStream_t stream) {
    const float* x   = (const float*)d_in[0];
    const int*   ei  = (const int*)d_in[1];
    const float* W1  = (const float*)d_in[2];
    const float* b1  = (const float*)d_in[3];
    const float* W2  = (const float*)d_in[4];
    const float* b2  = (const float*)d_in[5];
    const float* Wa1 = (const float*)d_in[6];
    const float* ba1 = (const float*)d_in[7];
    const float* Wa2 = (const float*)d_in[8];
    const float* ba2 = (const float*)d_in[9];
    const float* Ws  = (const float*)d_in[10];
    const float* bs  = (const float*)d_in[11];

    int N = in_sizes[0] / IN_DIM;
    int E = in_sizes[1] / 2;
    int Mpad = ((N + 127) / 128) * 128;
    int nt = Mpad / 128;

    float* out  = (float*)d_out;
    float* attr = out;
    float* st   = out + (size_t)N * IN_DIM;
    float* zout = st + (size_t)N * N;

    char* basep = (char*)d_ws;
    size_t off = 0;
    auto alloc = [&](size_t bytes) -> void* {
        void* p = basep + off;
        off = (off + bytes + 255) & ~(size_t)255;
        return p;
    };
    int*   colPad = (int*)alloc((size_t)N * DEGPAD * 4);
    int*   cursor = (int*)alloc((size_t)N * 4);
    __hip_bfloat16* Whi = (__hip_bfloat16*)alloc((size_t)WT_TOTAL * 2);
    __hip_bfloat16* Wlo = (__hip_bfloat16*)alloc((size_t)WT_TOTAL * 2);
    float* t128 = (float*)alloc((size_t)N * 128 * 4);
    float* t64  = (float*)alloc((size_t)N * 64 * 4);
    float* zp   = (float*)alloc((size_t)N * 64 * 4);
    __hip_bfloat16* Hhi  = (__hip_bfloat16*)alloc((size_t)Mpad * 128 * 2);
    __hip_bfloat16* Hlo  = (__hip_bfloat16*)alloc((size_t)Mpad * 128 * 2);
    __hip_bfloat16* AZhi = (__hip_bfloat16*)alloc((size_t)Mpad * 64 * 2);
    __hip_bfloat16* AZlo = (__hip_bfloat16*)alloc((size_t)Mpad * 64 * 2);
    __hip_bfloat16* AAhi = (__hip_bfloat16*)alloc((size_t)Mpad * 128 * 2);
    __hip_bfloat16* AAlo = (__hip_bfloat16*)alloc((size_t)Mpad * 128 * 2);
    __hip_bfloat16* Shi  = (__hip_bfloat16*)alloc((size_t)Mpad * 64 * 2);
    __hip_bfloat16* Slo  = (__hip_bfloat16*)alloc((size_t)Mpad * 64 * 2);

    dim3 b256(256);
    int spmm_grid = (N * 64 + 255) / 256;

    // 0. zero cursor (async memset node in the graph)
    hipMemsetAsync(cursor, 0, (size_t)N * 4, stream);
    // 1. prep: weight split + edge fill
    k_prep<<<dim3(1280), b256, 0, stream>>>(W1, W2, Wa1, Wa2, Ws, Whi, Wlo, ei, cursor, colPad, E);
    // 2. G1: t128 = dis ⊙ (x @ W1)
    k_g1<<<dim3(2 * nt), b256, 0, stream>>>(x, Whi, Wlo, cursor, t128, N);
    // 3. spmm1 (prescaled): H = relu(dis ⊙ Σ + b1) -> split
    k_spmm<128, true, true, 1><<<dim3(spmm_grid), b256, 0, stream>>>(
        t128, colPad, cursor, b1, nullptr, nullptr, Hhi, Hlo, N);
    // 4. G2: t64 = dis ⊙ (H @ W2)
    k_g2<<<dim3(nt), b256, 0, stream>>>(Hhi, Hlo, Whi, Wlo, cursor, t64, N);
    // 5. spmm2 (prescaled): z -> zout (fp32) and zp = dis ⊙ z
    k_spmm<64, true, true, 2><<<dim3(spmm_grid), b256, 0, stream>>>(
        t64, colPad, cursor, b2, zout, zp, nullptr, nullptr, N);
    // 6. spmm3 (prescaled): AZ = prop(zp) -> split
    k_spmm<64, false, false, 1><<<dim3(spmm_grid), b256, 0, stream>>>(
        zp, colPad, cursor, nullptr, nullptr, nullptr, AZhi, AZlo, N);
    // 7. G3 + G4
    k_g34<<<dim3(3 * nt), b256, 0, stream>>>(AZhi, AZlo, Whi, Wlo, ba1, bs, cursor, t128, Shi, Slo, N, Mpad);
    // 8. spmm4 (prescaled): AA = prop(t128) -> split
    k_spmm<128, false, false, 1><<<dim3(spmm_grid), b256, 0, stream>>>(
        t128, colPad, cursor, nullptr, nullptr, nullptr, AAhi, AAlo, N);
    // 9. tail: G5 (attr) + sst upper-triangle (struct)
    k_tail<<<dim3(16 * nt + nt * (nt + 1) / 2), b256, 0, stream>>>(
        AAhi, AAlo, Whi, Wlo, ba2, Shi, Slo, attr, st, N, Mpad);
}